// Round 7
// baseline (200.272 us; speedup 1.0000x reference)
//
#include <hip/hip_runtime.h>

typedef __attribute__((ext_vector_type(4))) float f32x4;
typedef __attribute__((ext_vector_type(8))) short bf16x8;

#define OPLANE 2916     // 54*54
#define NN 23328        // 8*54*54
#define KDIM 1152       // 128*9
#define PLANE 3136      // 56*56
#define LDP 72          // BK=64 LDS row (shorts): 144B stride
#define LDP2 136        // BK=128 LDS row (shorts): 272B stride -> 2-way max alias (free)

__device__ __forceinline__ unsigned short f2bf(float f) {
    unsigned u = __builtin_bit_cast(unsigned, f);
    u += 0x7fffu + ((u >> 16) & 1u);
    return (unsigned short)(u >> 16);
}

// ---- k_prep: weights -> bf16, K permuted to k' = ij*128 + ic (both GEMMs use same K order) ----
__global__ __launch_bounds__(256) void k_prep(const float* __restrict__ w0,
                                              const float* __restrict__ lw,
                                              unsigned short* __restrict__ b1t,
                                              unsigned short* __restrict__ b2t) {
    int idx = blockIdx.x * 256 + threadIdx.x;   // 442368 = 147456 + 294912
    if (idx < 147456) {
        int r = idx / KDIM, k = idx - r * KDIM;
        int ij = k >> 7, ic = k & 127;
        b1t[idx] = f2bf(w0[r * KDIM + ic * 9 + ij]);
    } else {
        int j = idx - 147456;
        int r = j / KDIM, k = j - r * KDIM;
        int ij = k >> 7, ic = k & 127;
        b2t[j] = f2bf(lw[r * KDIM + ic * 9 + ij]);
    }
}

// ---- k_nhwc: x NCHW fp32 -> NHWC bf16 ----
__global__ __launch_bounds__(256) void k_nhwc(const float* __restrict__ x,
                                              unsigned short* __restrict__ xnh) {
    __shared__ unsigned short lds[56 * 132];
    const int y = blockIdx.x, b = blockIdx.y, tid = threadIdx.x;
    for (int i = tid; i < 7168; i += 256) {
        int ic = i / 56, xc = i - ic * 56;
        lds[xc * 132 + ic] = f2bf(x[(b * 128 + ic) * PLANE + y * 56 + xc]);
    }
    __syncthreads();
    for (int i = tid; i < 7168; i += 256) {
        int xc = i >> 7, ic = i & 127;
        xnh[(b * PLANE + y * 56 + xc) * 128 + ic] = lds[xc * 132 + ic];
    }
}

// ---- gemm1 (fused im2col): h = relu(im2col(xnh) * b1t^T + b0) ---- (round-1 version)
__global__ __launch_bounds__(256) void k_gemm1(const unsigned short* __restrict__ xnh,
                                               const unsigned short* __restrict__ Bt,
                                               const float* __restrict__ bias,
                                               float* __restrict__ C) {
    __shared__ unsigned short As[64 * LDP];
    __shared__ unsigned short Bs[64 * LDP];
    const int tid = threadIdx.x;
    const int lane = tid & 63, wid = tid >> 6;
    const int wr = wid >> 1, wc = wid & 1;
    const int n0 = blockIdx.x * 64;     // 2 n-tiles
    const int m0 = blockIdx.y * 64;     // 392 m-tiles

    f32x4 acc[2][2];
    #pragma unroll
    for (int mt = 0; mt < 2; mt++)
        #pragma unroll
        for (int nt = 0; nt < 2; nt++) { acc[mt][nt][0]=0.f; acc[mt][nt][1]=0.f; acc[mt][nt][2]=0.f; acc[mt][nt][3]=0.f; }

    const int row = tid >> 2, q = tid & 3;
    const int p = m0 + row;
    const int b = p / PLANE; int rem = p - b * PLANE;
    const int y = rem / 56; const int xc = rem - y * 56;
    unsigned short* asw = &As[row * LDP + q * 16];
    const unsigned short* bg = Bt + (n0 + row) * KDIM + q * 16;
    unsigned short* bsw = &Bs[row * LDP + q * 16];
    const int lm = lane & 15, lq = lane >> 4;

    uint4 a0, a1, bv0, bv1;
    auto issue = [&](int it) {
        const int ij = it >> 1;
        const int di = ij / 3, dj = ij - di * 3;
        const int icb = (it & 1) << 6;
        a0 = make_uint4(0u,0u,0u,0u); a1 = make_uint4(0u,0u,0u,0u);
        bool valid = (y + di >= 1) && (y + di <= 56) && (xc + dj >= 1) && (xc + dj <= 56);
        if (valid) {
            const unsigned short* ap = xnh + (p + (di - 1) * 56 + (dj - 1)) * 128 + icb + q * 16;
            a0 = *(const uint4*)ap;
            a1 = *(const uint4*)(ap + 8);
        }
        bv0 = *(const uint4*)(bg + it * 64);
        bv1 = *(const uint4*)(bg + it * 64 + 8);
    };
    issue(0);

    #pragma unroll
    for (int it = 0; it < 18; it++) {
        __syncthreads();
        *(uint4*)(asw + 0) = a0;  *(uint4*)(asw + 8) = a1;
        *(uint4*)(bsw + 0) = bv0; *(uint4*)(bsw + 8) = bv1;
        __syncthreads();
        if (it < 17) issue(it + 1);
        #pragma unroll
        for (int kk = 0; kk < 64; kk += 32) {
            bf16x8 af[2], bf[2];
            #pragma unroll
            for (int mt = 0; mt < 2; mt++)
                af[mt] = *(const bf16x8*)&As[(wr * 32 + mt * 16 + lm) * LDP + kk + lq * 8];
            #pragma unroll
            for (int nt = 0; nt < 2; nt++)
                bf[nt] = *(const bf16x8*)&Bs[(wc * 32 + nt * 16 + lm) * LDP + kk + lq * 8];
            #pragma unroll
            for (int mt = 0; mt < 2; mt++)
                #pragma unroll
                for (int nt = 0; nt < 2; nt++)
                    acc[mt][nt] = __builtin_amdgcn_mfma_f32_16x16x32_bf16(af[mt], bf[nt], acc[mt][nt], 0, 0, 0);
        }
    }
    #pragma unroll
    for (int mt = 0; mt < 2; mt++) {
        int m = m0 + wr * 32 + mt * 16 + lq * 4;
        #pragma unroll
        for (int nt = 0; nt < 2; nt++) {
            int n = n0 + wc * 32 + nt * 16 + lm;
            float bb = bias[n];
            #pragma unroll
            for (int r = 0; r < 4; r++)
                C[(m + r) * 128 + n] = fmaxf(acc[mt][nt][r] + bb, 0.f);
        }
    }
}

// ---- k_conv2f: conv2 (NHWC h, LDS weights) + theta epilogue, fused ----
__global__ __launch_bounds__(256) void k_conv2f(const float* __restrict__ h,
                                                const float* __restrict__ w1,
                                                const int* __restrict__ check,
                                                float* __restrict__ o_out,
                                                float* __restrict__ o_th,
                                                float* __restrict__ o_ax,
                                                float* __restrict__ o_ay,
                                                float* __restrict__ sxy) {
    __shared__ float wlds[6912];        // [r][ij*128+ic]
    __shared__ float red[16 * 6 * 17];  // [pt][r][c] stride-17
    __shared__ float vals[96];
    const int tid = threadIdx.x;
    for (int idx = tid; idx < 6912; idx += 256) {
        int r = idx / KDIM, k = idx - r * KDIM;
        int ij = k >> 7, ic = k & 127;
        wlds[idx] = w1[r * KDIM + ic * 9 + ij];
    }
    __syncthreads();
    const int pt = tid >> 4, c = tid & 15;
    const int p = blockIdx.x * 16 + pt;
    int b = p / OPLANE; int rem = p - b * OPLANE; int oh = rem / 54; int ow = rem - oh * 54;
    const float4* h4 = (const float4*)h;
    const float4* w4 = (const float4*)wlds;
    float acc[6] = {0.f, 0.f, 0.f, 0.f, 0.f, 0.f};
    const int base_sp = b * PLANE + oh * 56 + ow;
    #pragma unroll
    for (int i = 0; i < 3; i++) {
        #pragma unroll
        for (int j = 0; j < 3; j++) {
            int sp = base_sp + i * 56 + j;
            float4 h0 = h4[sp * 32 + c * 2];
            float4 h1 = h4[sp * 32 + c * 2 + 1];
            int ij = i * 3 + j;
            #pragma unroll
            for (int r = 0; r < 6; r++) {
                float4 wa = w4[r * 288 + ij * 32 + c * 2];
                float4 wb = w4[r * 288 + ij * 32 + c * 2 + 1];
                acc[r] += h0.x * wa.x + h0.y * wa.y + h0.z * wa.z + h0.w * wa.w
                        + h1.x * wb.x + h1.y * wb.y + h1.z * wb.z + h1.w * wb.w;
            }
        }
    }
    #pragma unroll
    for (int r = 0; r < 6; r++) red[(pt * 6 + r) * 17 + c] = acc[r];
    __syncthreads();
    if (tid < 96) {
        const float* rp = &red[tid * 17];
        float s = 0.f;
        #pragma unroll
        for (int e = 0; e < 16; e++) s += rp[e];
        vals[tid] = s;
    }
    __syncthreads();
    if (tid < 16) {
        int p2 = blockIdx.x * 16 + tid;
        int b2 = p2 / OPLANE; int r2 = p2 - b2 * OPLANE; int oh2 = r2 / 54; int ow2 = r2 - oh2 * 54;
        float val[6];
        float s = 1.0f - (float)check[0];
        const float id6[6] = {1.f, 0.f, 0.f, 0.f, 1.f, 0.f};
        #pragma unroll
        for (int r = 0; r < 6; r++) val[r] = vals[tid * 6 + r] * s + id6[r];
        int n = (b2 * 54 + ow2) * 54 + oh2;
        #pragma unroll
        for (int r = 0; r < 6; r++) {
            o_out[((b2 * 6 + r) * 54 + oh2) * 54 + ow2] = val[r];
            o_th[n * 6 + r] = id6[r] - val[r];
        }
        const float bse[3] = {-2.f / 3.f, 0.f, 2.f / 3.f};
        #pragma unroll
        for (int i = 0; i < 3; i++)
            #pragma unroll
            for (int j = 0; j < 3; j++) {
                float gx = bse[j] * val[0] + bse[i] * val[1] + val[2];
                float gy = bse[j] * val[3] + bse[i] * val[4] + val[5];
                float ax = (gx + 1.f + (float)ow2) * (2.f / 55.f) - 1.f;
                float ay = (gy + 1.f + (float)oh2) * (2.f / 55.f) - 1.f;
                int ij = i * 3 + j;
                o_ax[n * 9 + ij] = ax;
                o_ay[n * 9 + ij] = ay;
                sxy[(n * 9 + ij) * 2 + 0] = (ax + 1.f) * 28.f - 0.5f;
                sxy[(n * 9 + ij) * 2 + 1] = (ay + 1.f) * 28.f - 0.5f;
            }
    }
}

// ---- k_sgemm: round-1 tiling (64 samples x 128 o, grid 2x365) with BK=128 ----
// 9 barrier-pairs instead of 18. Per thread/stage: 16 gather uint4 (sample chunk)
// + 8 weight uint4 (full 64-short half-row -> Ws fully covered; round-6 bug fix).
__global__ __launch_bounds__(256) void k_sgemm(const unsigned short* __restrict__ xnh,
                                               const unsigned short* __restrict__ Wt,
                                               const float* __restrict__ bias,
                                               const float* __restrict__ sxy,
                                               float* __restrict__ score) {
    __shared__ unsigned short Ss[64 * LDP2];    // samples: 64 rows x 128 k (17.4 KB)
    __shared__ unsigned short Ws[128 * LDP2];   // o-rows: 128 x 128 k (34.8 KB)
    const int tid = threadIdx.x;
    const int lane = tid & 63, wid = tid >> 6;
    const int wr = wid >> 1, wc = wid & 1;
    const int o0 = blockIdx.x * 128;
    const int s0 = blockIdx.y * 64;

    f32x4 acc[4][2];
    #pragma unroll
    for (int mt = 0; mt < 4; mt++)
        #pragma unroll
        for (int nt = 0; nt < 2; nt++) { acc[mt][nt][0]=0.f; acc[mt][nt][1]=0.f; acc[mt][nt][2]=0.f; acc[mt][nt][3]=0.f; }

    // gather assignment: row = sample (64), q = 32-ch chunk (4)
    const int row = tid >> 2, q = tid & 3;
    const int mp = min(s0 + row, NN - 1);           // score-linear sample id
    const int b = mp / OPLANE; const int rr = mp - b * OPLANE;
    const int ho = rr / 54, wo = rr - (rr / 54) * 54;
    const int n = (b * 54 + wo) * 54 + ho;          // theta-order id (sxy index)
    const int xbase = b * PLANE;
    unsigned short* ssw = &Ss[row * LDP2 + q * 32];
    // weight staging: wrow = o-row (128), wq = 64-short half (2)
    const int wrow = tid >> 1, wq = tid & 1;
    const unsigned short* wg = Wt + (o0 + wrow) * KDIM + wq * 64;
    unsigned short* wsw = &Ws[wrow * LDP2 + wq * 64];
    const int lm = lane & 15, lq = lane >> 4;

    // hoist all 9 sample coordinates out of the K-loop
    float2 sc[9];
    {
        const float* spp = sxy + n * 18;
        #pragma unroll
        for (int ij = 0; ij < 9; ij++) sc[ij] = *(const float2*)(spp + ij * 2);
    }

    int off0 = 0, off1 = 0, off2 = 0, off3 = 0;
    float wt0 = 0.f, wt1 = 0.f, wt2 = 0.f, wt3 = 0.f;
    auto mkoff = [&](int ij) {
        float sx = sc[ij].x, sy = sc[ij].y;
        float x0f = floorf(sx), y0f = floorf(sy);
        float wx = sx - x0f, wy = sy - y0f;
        int x0 = (int)x0f, y0 = (int)y0f;
        int x1 = x0 + 1, y1 = y0 + 1;
        float vx0 = (x0 >= 0 && x0 < 56) ? 1.f : 0.f;
        float vx1 = (x1 >= 0 && x1 < 56) ? 1.f : 0.f;
        float vy0 = (y0 >= 0 && y0 < 56) ? 1.f : 0.f;
        float vy1 = (y1 >= 0 && y1 < 56) ? 1.f : 0.f;
        int xc0 = min(max(x0, 0), 55), xc1 = min(max(x1, 0), 55);
        int yc0 = min(max(y0, 0), 55), yc1 = min(max(y1, 0), 55);
        off0 = (xbase + yc0 * 56 + xc0) << 7;
        off1 = (xbase + yc0 * 56 + xc1) << 7;
        off2 = (xbase + yc1 * 56 + xc0) << 7;
        off3 = (xbase + yc1 * 56 + xc1) << 7;
        wt0 = vy0 * vx0 * (1.f - wx) * (1.f - wy);
        wt1 = vy0 * vx1 * wx * (1.f - wy);
        wt2 = vy1 * vx0 * (1.f - wx) * wy;
        wt3 = vy1 * vx1 * wx * wy;
    };

    // stage registers: 4 corners x 2 chunk-halves x 2 uint4 + 8 weight uint4 (all named)
    uint4 g0a, g0b, g1a, g1b, g2a, g2b, g3a, g3b;   // first 16 ch of chunk
    uint4 t0a, t0b, t1a, t1b, t2a, t2b, t3a, t3b;   // second 16 ch of chunk
    uint4 w0v, w1v, w2v, w3v, w4v, w5v, w6v, w7v;   // full 64-short weight half-row
    auto issue = [&](int ij) {
        const int co = q * 32;                       // 32-ch chunk within the 128 of ij
        g0a = *(const uint4*)(xnh + off0 + co);      g0b = *(const uint4*)(xnh + off0 + co + 8);
        g1a = *(const uint4*)(xnh + off1 + co);      g1b = *(const uint4*)(xnh + off1 + co + 8);
        g2a = *(const uint4*)(xnh + off2 + co);      g2b = *(const uint4*)(xnh + off2 + co + 8);
        g3a = *(const uint4*)(xnh + off3 + co);      g3b = *(const uint4*)(xnh + off3 + co + 8);
        t0a = *(const uint4*)(xnh + off0 + co + 16); t0b = *(const uint4*)(xnh + off0 + co + 24);
        t1a = *(const uint4*)(xnh + off1 + co + 16); t1b = *(const uint4*)(xnh + off1 + co + 24);
        t2a = *(const uint4*)(xnh + off2 + co + 16); t2b = *(const uint4*)(xnh + off2 + co + 24);
        t3a = *(const uint4*)(xnh + off3 + co + 16); t3b = *(const uint4*)(xnh + off3 + co + 24);
        const unsigned short* wp = wg + ij * 128;
        w0v = *(const uint4*)(wp + 0);
        w1v = *(const uint4*)(wp + 8);
        w2v = *(const uint4*)(wp + 16);
        w3v = *(const uint4*)(wp + 24);
        w4v = *(const uint4*)(wp + 32);
        w5v = *(const uint4*)(wp + 40);
        w6v = *(const uint4*)(wp + 48);
        w7v = *(const uint4*)(wp + 56);
    };

    // blend one quartet (4 dwords = 8 ch) from the 4 corners' matching uint4s
    auto blend4 = [&](const uint4& c0, const uint4& c1, const uint4& c2, const uint4& c3) -> uint4 {
        unsigned dwv[4];
        const unsigned* u0p = (const unsigned*)&c0;
        const unsigned* u1p = (const unsigned*)&c1;
        const unsigned* u2p = (const unsigned*)&c2;
        const unsigned* u3p = (const unsigned*)&c3;
        #pragma unroll
        for (int d = 0; d < 4; d++) {
            unsigned u0 = u0p[d], u1 = u1p[d], u2 = u2p[d], u3 = u3p[d];
            float lo = wt0 * __builtin_bit_cast(float, u0 << 16)
                     + wt1 * __builtin_bit_cast(float, u1 << 16)
                     + wt2 * __builtin_bit_cast(float, u2 << 16)
                     + wt3 * __builtin_bit_cast(float, u3 << 16);
            float hi = wt0 * __builtin_bit_cast(float, u0 & 0xffff0000u)
                     + wt1 * __builtin_bit_cast(float, u1 & 0xffff0000u)
                     + wt2 * __builtin_bit_cast(float, u2 & 0xffff0000u)
                     + wt3 * __builtin_bit_cast(float, u3 & 0xffff0000u);
            dwv[d] = (unsigned)f2bf(lo) | ((unsigned)f2bf(hi) << 16);
        }
        return *(const uint4*)dwv;
    };

    mkoff(0);
    issue(0);

    #pragma unroll
    for (int it = 0; it < 9; it++) {
        uint4 o0v = blend4(g0a, g1a, g2a, g3a);
        uint4 o1v = blend4(g0b, g1b, g2b, g3b);
        uint4 o2v = blend4(t0a, t1a, t2a, t3a);
        uint4 o3v = blend4(t0b, t1b, t2b, t3b);
        __syncthreads();                      // prev MFMA reads of LDS done
        *(uint4*)(ssw + 0)  = o0v;
        *(uint4*)(ssw + 8)  = o1v;
        *(uint4*)(ssw + 16) = o2v;
        *(uint4*)(ssw + 24) = o3v;
        *(uint4*)(wsw + 0)  = w0v;
        *(uint4*)(wsw + 8)  = w1v;
        *(uint4*)(wsw + 16) = w2v;
        *(uint4*)(wsw + 24) = w3v;
        *(uint4*)(wsw + 32) = w4v;
        *(uint4*)(wsw + 40) = w5v;
        *(uint4*)(wsw + 48) = w6v;
        *(uint4*)(wsw + 56) = w7v;
        __syncthreads();
        if (it < 8) {                         // prefetch next ij stage
            mkoff(it + 1);
            issue(it + 1);
        }
        #pragma unroll
        for (int kk = 0; kk < 128; kk += 32) {
            bf16x8 wf[4], sf[2];
            #pragma unroll
            for (int mt = 0; mt < 4; mt++)
                wf[mt] = *(const bf16x8*)&Ws[(wr * 64 + mt * 16 + lm) * LDP2 + kk + lq * 8];
            #pragma unroll
            for (int nt = 0; nt < 2; nt++)
                sf[nt] = *(const bf16x8*)&Ss[(wc * 32 + nt * 16 + lm) * LDP2 + kk + lq * 8];
            #pragma unroll
            for (int mt = 0; mt < 4; mt++)
                #pragma unroll
                for (int nt = 0; nt < 2; nt++)
                    acc[mt][nt] = __builtin_amdgcn_mfma_f32_16x16x32_bf16(wf[mt], sf[nt], acc[mt][nt], 0, 0, 0);
        }
    }
    #pragma unroll
    for (int mt = 0; mt < 4; mt++) {
        #pragma unroll
        for (int r = 0; r < 4; r++) {
            int o = o0 + wr * 64 + mt * 16 + lq * 4 + r;
            float bb = bias[o];
            #pragma unroll
            for (int nt = 0; nt < 2; nt++) {
                int s = s0 + wc * 32 + nt * 16 + lm;
                if (s < NN) {
                    int sb = s / OPLANE;
                    int soff = s - sb * OPLANE;
                    score[(sb * 256 + o) * OPLANE + soff] = acc[mt][nt][r] + bb;
                }
            }
        }
    }
}

extern "C" void kernel_launch(void* const* d_in, const int* in_sizes, int n_in,
                              void* d_out, int out_size, void* d_ws, size_t ws_size,
                              hipStream_t stream) {
    const float* x  = (const float*)d_in[0];
    const float* w0 = (const float*)d_in[1];
    const float* b0 = (const float*)d_in[2];
    const float* w1 = (const float*)d_in[3];
    const float* lw = (const float*)d_in[4];
    const float* lb = (const float*)d_in[5];
    const int* check = (const int*)d_in[6];

    float* out   = (float*)d_out;
    float* score = out;                    // 8*256*54*54 = 5,971,968
    float* o_th  = out + 5971968;          // 139,968
    float* o_out = out + 6111936;          // 139,968
    float* o_ax  = out + 6251904;          // 209,952
    float* o_ay  = out + 6461856;          // 209,952

    char* wsb = (char*)d_ws;
    float* h   = (float*)wsb;                                    //  12,845,056 B
    unsigned short* xnh = (unsigned short*)(wsb + 12845056);     //   6,422,528 B
    unsigned short* b1t = (unsigned short*)(wsb + 19267584);     //     294,912 B
    unsigned short* b2t = (unsigned short*)(wsb + 19562496);     //     589,824 B
    float* sxy = (float*)(wsb + 20152320);                       //   1,679,616 B -> 21.8 MB total

    k_prep<<<1728, 256, 0, stream>>>(w0, lw, b1t, b2t);
    k_nhwc<<<dim3(56, 8), 256, 0, stream>>>(x, xnh);
    k_gemm1<<<dim3(2, 392), 256, 0, stream>>>(xnh, b1t, b0, h);
    k_conv2f<<<1458, 256, 0, stream>>>(h, w1, check, o_out, o_th, o_ax, o_ay, sxy);
    k_sgemm<<<dim3(2, 365), 256, 0, stream>>>(xnh, b2t, lb, sxy, score);
}

// Round 8
// 175.793 us; speedup vs baseline: 1.1392x; 1.1392x over previous
//
#include <hip/hip_runtime.h>

typedef __attribute__((ext_vector_type(4))) float f32x4;
typedef __attribute__((ext_vector_type(8))) short bf16x8;

#define OPLANE 2916     // 54*54
#define NN 23328        // 8*54*54
#define KDIM 1152       // 128*9
#define PLANE 3136      // 56*56
#define LDP 72          // LDS row (shorts): 144B stride -> 2-way max alias (free)

__device__ __forceinline__ unsigned short f2bf(float f) {
    unsigned u = __builtin_bit_cast(unsigned, f);
    u += 0x7fffu + ((u >> 16) & 1u);
    return (unsigned short)(u >> 16);
}

// ---- k_prep: weights -> bf16, K permuted to k' = ij*128 + ic (both GEMMs use same K order) ----
__global__ __launch_bounds__(256) void k_prep(const float* __restrict__ w0,
                                              const float* __restrict__ lw,
                                              unsigned short* __restrict__ b1t,
                                              unsigned short* __restrict__ b2t) {
    int idx = blockIdx.x * 256 + threadIdx.x;   // 442368 = 147456 + 294912
    if (idx < 147456) {
        int r = idx / KDIM, k = idx - r * KDIM;
        int ij = k >> 7, ic = k & 127;
        b1t[idx] = f2bf(w0[r * KDIM + ic * 9 + ij]);
    } else {
        int j = idx - 147456;
        int r = j / KDIM, k = j - r * KDIM;
        int ij = k >> 7, ic = k & 127;
        b2t[j] = f2bf(lw[r * KDIM + ic * 9 + ij]);
    }
}

// ---- k_nhwc: x NCHW fp32 -> NHWC bf16 ----
__global__ __launch_bounds__(256) void k_nhwc(const float* __restrict__ x,
                                              unsigned short* __restrict__ xnh) {
    __shared__ unsigned short lds[56 * 132];
    const int y = blockIdx.x, b = blockIdx.y, tid = threadIdx.x;
    for (int i = tid; i < 7168; i += 256) {
        int ic = i / 56, xc = i - ic * 56;
        lds[xc * 132 + ic] = f2bf(x[(b * 128 + ic) * PLANE + y * 56 + xc]);
    }
    __syncthreads();
    for (int i = tid; i < 7168; i += 256) {
        int xc = i >> 7, ic = i & 127;
        xnh[(b * PLANE + y * 56 + xc) * 128 + ic] = lds[xc * 132 + ic];
    }
}

// ---- gemm1 (fused im2col): h = relu(im2col(xnh) * b1t^T + b0) ---- (round-1 version)
__global__ __launch_bounds__(256) void k_gemm1(const unsigned short* __restrict__ xnh,
                                               const unsigned short* __restrict__ Bt,
                                               const float* __restrict__ bias,
                                               float* __restrict__ C) {
    __shared__ unsigned short As[64 * LDP];
    __shared__ unsigned short Bs[64 * LDP];
    const int tid = threadIdx.x;
    const int lane = tid & 63, wid = tid >> 6;
    const int wr = wid >> 1, wc = wid & 1;
    const int n0 = blockIdx.x * 64;     // 2 n-tiles
    const int m0 = blockIdx.y * 64;     // 392 m-tiles

    f32x4 acc[2][2];
    #pragma unroll
    for (int mt = 0; mt < 2; mt++)
        #pragma unroll
        for (int nt = 0; nt < 2; nt++) { acc[mt][nt][0]=0.f; acc[mt][nt][1]=0.f; acc[mt][nt][2]=0.f; acc[mt][nt][3]=0.f; }

    const int row = tid >> 2, q = tid & 3;
    const int p = m0 + row;
    const int b = p / PLANE; int rem = p - b * PLANE;
    const int y = rem / 56; const int xc = rem - y * 56;
    unsigned short* asw = &As[row * LDP + q * 16];
    const unsigned short* bg = Bt + (n0 + row) * KDIM + q * 16;
    unsigned short* bsw = &Bs[row * LDP + q * 16];
    const int lm = lane & 15, lq = lane >> 4;

    uint4 a0, a1, bv0, bv1;
    auto issue = [&](int it) {
        const int ij = it >> 1;
        const int di = ij / 3, dj = ij - di * 3;
        const int icb = (it & 1) << 6;
        a0 = make_uint4(0u,0u,0u,0u); a1 = make_uint4(0u,0u,0u,0u);
        bool valid = (y + di >= 1) && (y + di <= 56) && (xc + dj >= 1) && (xc + dj <= 56);
        if (valid) {
            const unsigned short* ap = xnh + (p + (di - 1) * 56 + (dj - 1)) * 128 + icb + q * 16;
            a0 = *(const uint4*)ap;
            a1 = *(const uint4*)(ap + 8);
        }
        bv0 = *(const uint4*)(bg + it * 64);
        bv1 = *(const uint4*)(bg + it * 64 + 8);
    };
    issue(0);

    #pragma unroll
    for (int it = 0; it < 18; it++) {
        __syncthreads();
        *(uint4*)(asw + 0) = a0;  *(uint4*)(asw + 8) = a1;
        *(uint4*)(bsw + 0) = bv0; *(uint4*)(bsw + 8) = bv1;
        __syncthreads();
        if (it < 17) issue(it + 1);
        #pragma unroll
        for (int kk = 0; kk < 64; kk += 32) {
            bf16x8 af[2], bf[2];
            #pragma unroll
            for (int mt = 0; mt < 2; mt++)
                af[mt] = *(const bf16x8*)&As[(wr * 32 + mt * 16 + lm) * LDP + kk + lq * 8];
            #pragma unroll
            for (int nt = 0; nt < 2; nt++)
                bf[nt] = *(const bf16x8*)&Bs[(wc * 32 + nt * 16 + lm) * LDP + kk + lq * 8];
            #pragma unroll
            for (int mt = 0; mt < 2; mt++)
                #pragma unroll
                for (int nt = 0; nt < 2; nt++)
                    acc[mt][nt] = __builtin_amdgcn_mfma_f32_16x16x32_bf16(af[mt], bf[nt], acc[mt][nt], 0, 0, 0);
        }
    }
    #pragma unroll
    for (int mt = 0; mt < 2; mt++) {
        int m = m0 + wr * 32 + mt * 16 + lq * 4;
        #pragma unroll
        for (int nt = 0; nt < 2; nt++) {
            int n = n0 + wc * 32 + nt * 16 + lm;
            float bb = bias[n];
            #pragma unroll
            for (int r = 0; r < 4; r++)
                C[(m + r) * 128 + n] = fmaxf(acc[mt][nt][r] + bb, 0.f);
        }
    }
}

// ---- k_conv2f: conv2 (NHWC h, LDS weights) + theta epilogue, fused ----
__global__ __launch_bounds__(256) void k_conv2f(const float* __restrict__ h,
                                                const float* __restrict__ w1,
                                                const int* __restrict__ check,
                                                float* __restrict__ o_out,
                                                float* __restrict__ o_th,
                                                float* __restrict__ o_ax,
                                                float* __restrict__ o_ay,
                                                float* __restrict__ sxy) {
    __shared__ float wlds[6912];        // [r][ij*128+ic]
    __shared__ float red[16 * 6 * 17];  // [pt][r][c] stride-17
    __shared__ float vals[96];
    const int tid = threadIdx.x;
    for (int idx = tid; idx < 6912; idx += 256) {
        int r = idx / KDIM, k = idx - r * KDIM;
        int ij = k >> 7, ic = k & 127;
        wlds[idx] = w1[r * KDIM + ic * 9 + ij];
    }
    __syncthreads();
    const int pt = tid >> 4, c = tid & 15;
    const int p = blockIdx.x * 16 + pt;
    int b = p / OPLANE; int rem = p - b * OPLANE; int oh = rem / 54; int ow = rem - oh * 54;
    const float4* h4 = (const float4*)h;
    const float4* w4 = (const float4*)wlds;
    float acc[6] = {0.f, 0.f, 0.f, 0.f, 0.f, 0.f};
    const int base_sp = b * PLANE + oh * 56 + ow;
    #pragma unroll
    for (int i = 0; i < 3; i++) {
        #pragma unroll
        for (int j = 0; j < 3; j++) {
            int sp = base_sp + i * 56 + j;
            float4 h0 = h4[sp * 32 + c * 2];
            float4 h1 = h4[sp * 32 + c * 2 + 1];
            int ij = i * 3 + j;
            #pragma unroll
            for (int r = 0; r < 6; r++) {
                float4 wa = w4[r * 288 + ij * 32 + c * 2];
                float4 wb = w4[r * 288 + ij * 32 + c * 2 + 1];
                acc[r] += h0.x * wa.x + h0.y * wa.y + h0.z * wa.z + h0.w * wa.w
                        + h1.x * wb.x + h1.y * wb.y + h1.z * wb.z + h1.w * wb.w;
            }
        }
    }
    #pragma unroll
    for (int r = 0; r < 6; r++) red[(pt * 6 + r) * 17 + c] = acc[r];
    __syncthreads();
    if (tid < 96) {
        const float* rp = &red[tid * 17];
        float s = 0.f;
        #pragma unroll
        for (int e = 0; e < 16; e++) s += rp[e];
        vals[tid] = s;
    }
    __syncthreads();
    if (tid < 16) {
        int p2 = blockIdx.x * 16 + tid;
        int b2 = p2 / OPLANE; int r2 = p2 - b2 * OPLANE; int oh2 = r2 / 54; int ow2 = r2 - oh2 * 54;
        float val[6];
        float s = 1.0f - (float)check[0];
        const float id6[6] = {1.f, 0.f, 0.f, 0.f, 1.f, 0.f};
        #pragma unroll
        for (int r = 0; r < 6; r++) val[r] = vals[tid * 6 + r] * s + id6[r];
        int n = (b2 * 54 + ow2) * 54 + oh2;
        #pragma unroll
        for (int r = 0; r < 6; r++) {
            o_out[((b2 * 6 + r) * 54 + oh2) * 54 + ow2] = val[r];
            o_th[n * 6 + r] = id6[r] - val[r];
        }
        const float bse[3] = {-2.f / 3.f, 0.f, 2.f / 3.f};
        #pragma unroll
        for (int i = 0; i < 3; i++)
            #pragma unroll
            for (int j = 0; j < 3; j++) {
                float gx = bse[j] * val[0] + bse[i] * val[1] + val[2];
                float gy = bse[j] * val[3] + bse[i] * val[4] + val[5];
                float ax = (gx + 1.f + (float)ow2) * (2.f / 55.f) - 1.f;
                float ay = (gy + 1.f + (float)oh2) * (2.f / 55.f) - 1.f;
                int ij = i * 3 + j;
                o_ax[n * 9 + ij] = ax;
                o_ay[n * 9 + ij] = ay;
                sxy[(n * 9 + ij) * 2 + 0] = (ax + 1.f) * 28.f - 0.5f;
                sxy[(n * 9 + ij) * 2 + 1] = (ay + 1.f) * 28.f - 0.5f;
            }
    }
}

// ---- k_sgemm v3: 512 threads / 8 waves, tile 32 samples x FULL o=256, grid 729 ----
// No o-redundancy (gather+blend once per sample) AND 2x TLP (22.8 waves/CU).
// Round-1's proven schedule: blend -> barrier -> LDS write -> barrier -> issue(t+1) -> MFMA.
// 729*32 = 23328 exact: no bounds checks. LDS 41.5 KB.
__global__ __launch_bounds__(512) void k_sgemm(const unsigned short* __restrict__ xnh,
                                               const unsigned short* __restrict__ Wt,
                                               const float* __restrict__ bias,
                                               const float* __restrict__ sxy,
                                               float* __restrict__ score) {
    __shared__ unsigned short Ss[32 * LDP];     // samples: 32 x 64k (4.6 KB)
    __shared__ unsigned short Ws[256 * LDP];    // o-rows: 256 x 64k (36.9 KB)
    const int tid = threadIdx.x;
    const int lane = tid & 63, wid = tid >> 6;  // 8 waves
    const int wr = wid >> 1;                    // o-quarter [0,4) -> 64 o-rows
    const int wc = wid & 1;                     // s-half [0,2) -> 16 samples
    const int s0 = blockIdx.x * 32;

    f32x4 acc[4];
    #pragma unroll
    for (int mt = 0; mt < 4; mt++) { acc[mt][0]=0.f; acc[mt][1]=0.f; acc[mt][2]=0.f; acc[mt][3]=0.f; }

    // gather assignment: row = sample (32), q = 4-ch chunk (16) -> 8B per corner
    const int row = tid >> 4, q = tid & 15;
    const int mp = s0 + row;                    // < 23328 always (729*32 exact)
    const int b = mp / OPLANE; const int rr = mp - b * OPLANE;
    const int ho = rr / 54, wo = rr - (rr / 54) * 54;
    const int n = (b * 54 + wo) * 54 + ho;      // theta-order id (sxy index)
    const int xbase = b * PLANE;
    unsigned short* ssw = &Ss[row * LDP + q * 4];
    // weight staging: wrow = o-row (256), wq = 32-short half (2)
    const int wrow = tid >> 1, wq = tid & 1;
    const unsigned short* wg = Wt + wrow * KDIM + wq * 32;
    unsigned short* wsw = &Ws[wrow * LDP + wq * 32];
    const int lm = lane & 15, lq = lane >> 4;

    // hoist all 9 sample coordinates out of the K-loop
    float2 sc[9];
    {
        const float* spp = sxy + n * 18;
        #pragma unroll
        for (int ij = 0; ij < 9; ij++) sc[ij] = *(const float2*)(spp + ij * 2);
    }

    int off0 = 0, off1 = 0, off2 = 0, off3 = 0;
    float wt0 = 0.f, wt1 = 0.f, wt2 = 0.f, wt3 = 0.f;
    auto mkoff = [&](int ij) {
        float sx = sc[ij].x, sy = sc[ij].y;
        float x0f = floorf(sx), y0f = floorf(sy);
        float wx = sx - x0f, wy = sy - y0f;
        int x0 = (int)x0f, y0 = (int)y0f;
        int x1 = x0 + 1, y1 = y0 + 1;
        float vx0 = (x0 >= 0 && x0 < 56) ? 1.f : 0.f;
        float vx1 = (x1 >= 0 && x1 < 56) ? 1.f : 0.f;
        float vy0 = (y0 >= 0 && y0 < 56) ? 1.f : 0.f;
        float vy1 = (y1 >= 0 && y1 < 56) ? 1.f : 0.f;
        int xc0 = min(max(x0, 0), 55), xc1 = min(max(x1, 0), 55);
        int yc0 = min(max(y0, 0), 55), yc1 = min(max(y1, 0), 55);
        off0 = (xbase + yc0 * 56 + xc0) << 7;
        off1 = (xbase + yc0 * 56 + xc1) << 7;
        off2 = (xbase + yc1 * 56 + xc0) << 7;
        off3 = (xbase + yc1 * 56 + xc1) << 7;
        wt0 = vy0 * vx0 * (1.f - wx) * (1.f - wy);
        wt1 = vy0 * vx1 * wx * (1.f - wy);
        wt2 = vy1 * vx0 * (1.f - wx) * wy;
        wt3 = vy1 * vx1 * wx * wy;
    };

    uint2 p0, p1, p2, p3;                        // 4 corners x 8B (4 ch)
    uint4 w0v, w1v, w2v, w3v;                    // 32 weight shorts
    auto issue = [&](int it) {
        const int co = ((it & 1) << 6) + q * 4;  // channel offset within ij's 128
        p0 = *(const uint2*)(xnh + off0 + co);
        p1 = *(const uint2*)(xnh + off1 + co);
        p2 = *(const uint2*)(xnh + off2 + co);
        p3 = *(const uint2*)(xnh + off3 + co);
        const unsigned short* wp = wg + it * 64;
        w0v = *(const uint4*)(wp + 0);
        w1v = *(const uint4*)(wp + 8);
        w2v = *(const uint4*)(wp + 16);
        w3v = *(const uint4*)(wp + 24);
    };

    // blend 2 dwords (4 ch) from the 4 corner uint2s
    auto blend2 = [&]() -> uint2 {
        unsigned dwv[2];
        const unsigned* u0p = (const unsigned*)&p0;
        const unsigned* u1p = (const unsigned*)&p1;
        const unsigned* u2p = (const unsigned*)&p2;
        const unsigned* u3p = (const unsigned*)&p3;
        #pragma unroll
        for (int d = 0; d < 2; d++) {
            unsigned u0 = u0p[d], u1 = u1p[d], u2 = u2p[d], u3 = u3p[d];
            float lo = wt0 * __builtin_bit_cast(float, u0 << 16)
                     + wt1 * __builtin_bit_cast(float, u1 << 16)
                     + wt2 * __builtin_bit_cast(float, u2 << 16)
                     + wt3 * __builtin_bit_cast(float, u3 << 16);
            float hi = wt0 * __builtin_bit_cast(float, u0 & 0xffff0000u)
                     + wt1 * __builtin_bit_cast(float, u1 & 0xffff0000u)
                     + wt2 * __builtin_bit_cast(float, u2 & 0xffff0000u)
                     + wt3 * __builtin_bit_cast(float, u3 & 0xffff0000u);
            dwv[d] = (unsigned)f2bf(lo) | ((unsigned)f2bf(hi) << 16);
        }
        uint2 r; r.x = dwv[0]; r.y = dwv[1];
        return r;
    };

    mkoff(0);
    issue(0);

    #pragma unroll
    for (int it = 0; it < 18; it++) {
        uint2 sv = blend2();                  // vmcnt wait here (under prev MFMA)
        __syncthreads();                      // prev MFMA reads of LDS done
        *(uint2*)ssw = sv;
        *(uint4*)(wsw + 0)  = w0v;
        *(uint4*)(wsw + 8)  = w1v;
        *(uint4*)(wsw + 16) = w2v;
        *(uint4*)(wsw + 24) = w3v;
        __syncthreads();
        if (it < 17) {                        // prefetch next stage
            if (((it + 1) & 1) == 0) mkoff((it + 1) >> 1);
            issue(it + 1);
        }
        #pragma unroll
        for (int kk = 0; kk < 64; kk += 32) {
            bf16x8 wf[4], sf;
            #pragma unroll
            for (int mt = 0; mt < 4; mt++)
                wf[mt] = *(const bf16x8*)&Ws[(wr * 64 + mt * 16 + lm) * LDP + kk + lq * 8];
            sf = *(const bf16x8*)&Ss[(wc * 16 + lm) * LDP + kk + lq * 8];
            #pragma unroll
            for (int mt = 0; mt < 4; mt++)
                acc[mt] = __builtin_amdgcn_mfma_f32_16x16x32_bf16(wf[mt], sf, acc[mt], 0, 0, 0);
        }
    }
    #pragma unroll
    for (int mt = 0; mt < 4; mt++) {
        #pragma unroll
        for (int r = 0; r < 4; r++) {
            int o = wr * 64 + mt * 16 + lq * 4 + r;
            float bb = bias[o];
            int s = s0 + wc * 16 + lm;
            int sb = s / OPLANE;
            int soff = s - sb * OPLANE;
            score[(sb * 256 + o) * OPLANE + soff] = acc[mt][r] + bb;
        }
    }
}

extern "C" void kernel_launch(void* const* d_in, const int* in_sizes, int n_in,
                              void* d_out, int out_size, void* d_ws, size_t ws_size,
                              hipStream_t stream) {
    const float* x  = (const float*)d_in[0];
    const float* w0 = (const float*)d_in[1];
    const float* b0 = (const float*)d_in[2];
    const float* w1 = (const float*)d_in[3];
    const float* lw = (const float*)d_in[4];
    const float* lb = (const float*)d_in[5];
    const int* check = (const int*)d_in[6];

    float* out   = (float*)d_out;
    float* score = out;                    // 8*256*54*54 = 5,971,968
    float* o_th  = out + 5971968;          // 139,968
    float* o_out = out + 6111936;          // 139,968
    float* o_ax  = out + 6251904;          // 209,952
    float* o_ay  = out + 6461856;          // 209,952

    char* wsb = (char*)d_ws;
    float* h   = (float*)wsb;                                    //  12,845,056 B
    unsigned short* xnh = (unsigned short*)(wsb + 12845056);     //   6,422,528 B
    unsigned short* b1t = (unsigned short*)(wsb + 19267584);     //     294,912 B
    unsigned short* b2t = (unsigned short*)(wsb + 19562496);     //     589,824 B
    float* sxy = (float*)(wsb + 20152320);                       //   1,679,616 B -> 21.8 MB total

    k_prep<<<1728, 256, 0, stream>>>(w0, lw, b1t, b2t);
    k_nhwc<<<dim3(56, 8), 256, 0, stream>>>(x, xnh);
    k_gemm1<<<dim3(2, 392), 256, 0, stream>>>(xnh, b1t, b0, h);
    k_conv2f<<<1458, 256, 0, stream>>>(h, w1, check, o_out, o_th, o_ax, o_ay, sxy);
    k_sgemm<<<729, 512, 0, stream>>>(xnh, b2t, lb, sxy, score);
}

// Round 9
// 167.015 us; speedup vs baseline: 1.1991x; 1.0526x over previous
//
#include <hip/hip_runtime.h>

typedef __attribute__((ext_vector_type(4))) float f32x4;
typedef __attribute__((ext_vector_type(8))) short bf16x8;

#define OPLANE 2916     // 54*54
#define NN 23328        // 8*54*54
#define KDIM 1152       // 128*9
#define PLANE 3136      // 56*56
#define LDP 72          // LDS row (shorts): 144B stride -> 2-way max alias (free)

__device__ __forceinline__ unsigned short f2bf(float f) {
    unsigned u = __builtin_bit_cast(unsigned, f);
    u += 0x7fffu + ((u >> 16) & 1u);
    return (unsigned short)(u >> 16);
}

// ---- k_pre: fused {weights->bf16 K-permute} + {x NCHW fp32 -> NHWC bf16} ----
// blocks [0,1728): prep; blocks [1728,2176): nhwc transpose. One launch gap saved.
__global__ __launch_bounds__(256) void k_pre(const float* __restrict__ x,
                                             const float* __restrict__ w0,
                                             const float* __restrict__ lw,
                                             unsigned short* __restrict__ xnh,
                                             unsigned short* __restrict__ b1t,
                                             unsigned short* __restrict__ b2t) {
    __shared__ unsigned short lds[56 * 132];
    if (blockIdx.x < 1728) {
        int idx = blockIdx.x * 256 + threadIdx.x;   // 442368 = 147456 + 294912
        if (idx < 147456) {
            int r = idx / KDIM, k = idx - r * KDIM;
            int ij = k >> 7, ic = k & 127;
            b1t[idx] = f2bf(w0[r * KDIM + ic * 9 + ij]);
        } else {
            int j = idx - 147456;
            int r = j / KDIM, k = j - r * KDIM;
            int ij = k >> 7, ic = k & 127;
            b2t[j] = f2bf(lw[r * KDIM + ic * 9 + ij]);
        }
    } else {
        const int bid = blockIdx.x - 1728;
        const int y = bid % 56, b = bid / 56, tid = threadIdx.x;
        for (int i = tid; i < 7168; i += 256) {
            int ic = i / 56, xc = i - ic * 56;
            lds[xc * 132 + ic] = f2bf(x[(b * 128 + ic) * PLANE + y * 56 + xc]);
        }
        __syncthreads();
        for (int i = tid; i < 7168; i += 256) {
            int xc = i >> 7, ic = i & 127;
            xnh[(b * PLANE + y * 56 + xc) * 128 + ic] = lds[xc * 132 + ic];
        }
    }
}

// ---- gemm1 (fused im2col): h = relu(im2col(xnh) * b1t^T + b0) ----
// n-merged: grid 392 x 512 threads, 64x128 tile, 8 waves of 32x32.
// Same per-wave LDS/MFMA patterns as the proven 2-way-split version; A-tile
// staged ONCE instead of twice (dedup), waves/CU unchanged at 12.25.
__global__ __launch_bounds__(512) void k_gemm1(const unsigned short* __restrict__ xnh,
                                               const unsigned short* __restrict__ Bt,
                                               const float* __restrict__ bias,
                                               float* __restrict__ C) {
    __shared__ unsigned short As[64 * LDP];
    __shared__ unsigned short Bs[128 * LDP];
    const int tid = threadIdx.x;
    const int lane = tid & 63, wid = tid >> 6;   // 8 waves
    const int wr = wid >> 2, wc = wid & 3;       // 2 m-halves x 4 n-quarters
    const int m0 = blockIdx.x * 64;              // 392 m-tiles (392*64 = 25088 exact)

    f32x4 acc[2][2];
    #pragma unroll
    for (int mt = 0; mt < 2; mt++)
        #pragma unroll
        for (int nt = 0; nt < 2; nt++) { acc[mt][nt][0]=0.f; acc[mt][nt][1]=0.f; acc[mt][nt][2]=0.f; acc[mt][nt][3]=0.f; }

    // A staging: row = sample (64), 8 threads/row, 8 shorts (1 uint4) each
    const int row = tid >> 3, q = tid & 7;
    const int p = m0 + row;
    const int b = p / PLANE; int rem = p - b * PLANE;
    const int y = rem / 56; const int xc = rem - y * 56;
    unsigned short* asw = &As[row * LDP + q * 8];
    // B staging: 128 rows, 4 threads/row, 16 shorts (2 uint4) each
    const int brow = tid >> 2, bq = tid & 3;
    const unsigned short* bg = Bt + brow * KDIM + bq * 16;
    unsigned short* bsw = &Bs[brow * LDP + bq * 16];
    const int lm = lane & 15, lq = lane >> 4;

    uint4 a0, bv0, bv1;
    auto issue = [&](int it) {
        const int ij = it >> 1;
        const int di = ij / 3, dj = ij - di * 3;
        const int icb = (it & 1) << 6;
        a0 = make_uint4(0u,0u,0u,0u);
        bool valid = (y + di >= 1) && (y + di <= 56) && (xc + dj >= 1) && (xc + dj <= 56);
        if (valid) {
            const unsigned short* ap = xnh + (p + (di - 1) * 56 + (dj - 1)) * 128 + icb + q * 8;
            a0 = *(const uint4*)ap;
        }
        bv0 = *(const uint4*)(bg + it * 64);
        bv1 = *(const uint4*)(bg + it * 64 + 8);
    };
    issue(0);

    #pragma unroll
    for (int it = 0; it < 18; it++) {
        __syncthreads();
        *(uint4*)asw = a0;
        *(uint4*)(bsw + 0) = bv0; *(uint4*)(bsw + 8) = bv1;
        __syncthreads();
        if (it < 17) issue(it + 1);
        #pragma unroll
        for (int kk = 0; kk < 64; kk += 32) {
            bf16x8 af[2], bf[2];
            #pragma unroll
            for (int mt = 0; mt < 2; mt++)
                af[mt] = *(const bf16x8*)&As[(wr * 32 + mt * 16 + lm) * LDP + kk + lq * 8];
            #pragma unroll
            for (int nt = 0; nt < 2; nt++)
                bf[nt] = *(const bf16x8*)&Bs[(wc * 32 + nt * 16 + lm) * LDP + kk + lq * 8];
            #pragma unroll
            for (int mt = 0; mt < 2; mt++)
                #pragma unroll
                for (int nt = 0; nt < 2; nt++)
                    acc[mt][nt] = __builtin_amdgcn_mfma_f32_16x16x32_bf16(af[mt], bf[nt], acc[mt][nt], 0, 0, 0);
        }
    }
    #pragma unroll
    for (int mt = 0; mt < 2; mt++) {
        int m = m0 + wr * 32 + mt * 16 + lq * 4;
        #pragma unroll
        for (int nt = 0; nt < 2; nt++) {
            int n = wc * 32 + nt * 16 + lm;
            float bb = bias[n];
            #pragma unroll
            for (int r = 0; r < 4; r++)
                C[(m + r) * 128 + n] = fmaxf(acc[mt][nt][r] + bb, 0.f);
        }
    }
}

// ---- k_conv2f: conv2 (NHWC h, LDS weights) + theta epilogue, fused ----
__global__ __launch_bounds__(256) void k_conv2f(const float* __restrict__ h,
                                                const float* __restrict__ w1,
                                                const int* __restrict__ check,
                                                float* __restrict__ o_out,
                                                float* __restrict__ o_th,
                                                float* __restrict__ o_ax,
                                                float* __restrict__ o_ay,
                                                float* __restrict__ sxy) {
    __shared__ float wlds[6912];        // [r][ij*128+ic]
    __shared__ float red[16 * 6 * 17];  // [pt][r][c] stride-17
    __shared__ float vals[96];
    const int tid = threadIdx.x;
    for (int idx = tid; idx < 6912; idx += 256) {
        int r = idx / KDIM, k = idx - r * KDIM;
        int ij = k >> 7, ic = k & 127;
        wlds[idx] = w1[r * KDIM + ic * 9 + ij];
    }
    __syncthreads();
    const int pt = tid >> 4, c = tid & 15;
    const int p = blockIdx.x * 16 + pt;
    int b = p / OPLANE; int rem = p - b * OPLANE; int oh = rem / 54; int ow = rem - oh * 54;
    const float4* h4 = (const float4*)h;
    const float4* w4 = (const float4*)wlds;
    float acc[6] = {0.f, 0.f, 0.f, 0.f, 0.f, 0.f};
    const int base_sp = b * PLANE + oh * 56 + ow;
    #pragma unroll
    for (int i = 0; i < 3; i++) {
        #pragma unroll
        for (int j = 0; j < 3; j++) {
            int sp = base_sp + i * 56 + j;
            float4 h0 = h4[sp * 32 + c * 2];
            float4 h1 = h4[sp * 32 + c * 2 + 1];
            int ij = i * 3 + j;
            #pragma unroll
            for (int r = 0; r < 6; r++) {
                float4 wa = w4[r * 288 + ij * 32 + c * 2];
                float4 wb = w4[r * 288 + ij * 32 + c * 2 + 1];
                acc[r] += h0.x * wa.x + h0.y * wa.y + h0.z * wa.z + h0.w * wa.w
                        + h1.x * wb.x + h1.y * wb.y + h1.z * wb.z + h1.w * wb.w;
            }
        }
    }
    #pragma unroll
    for (int r = 0; r < 6; r++) red[(pt * 6 + r) * 17 + c] = acc[r];
    __syncthreads();
    if (tid < 96) {
        const float* rp = &red[tid * 17];
        float s = 0.f;
        #pragma unroll
        for (int e = 0; e < 16; e++) s += rp[e];
        vals[tid] = s;
    }
    __syncthreads();
    if (tid < 16) {
        int p2 = blockIdx.x * 16 + tid;
        int b2 = p2 / OPLANE; int r2 = p2 - b2 * OPLANE; int oh2 = r2 / 54; int ow2 = r2 - oh2 * 54;
        float val[6];
        float s = 1.0f - (float)check[0];
        const float id6[6] = {1.f, 0.f, 0.f, 0.f, 1.f, 0.f};
        #pragma unroll
        for (int r = 0; r < 6; r++) val[r] = vals[tid * 6 + r] * s + id6[r];
        int n = (b2 * 54 + ow2) * 54 + oh2;
        #pragma unroll
        for (int r = 0; r < 6; r++) {
            o_out[((b2 * 6 + r) * 54 + oh2) * 54 + ow2] = val[r];
            o_th[n * 6 + r] = id6[r] - val[r];
        }
        const float bse[3] = {-2.f / 3.f, 0.f, 2.f / 3.f};
        #pragma unroll
        for (int i = 0; i < 3; i++)
            #pragma unroll
            for (int j = 0; j < 3; j++) {
                float gx = bse[j] * val[0] + bse[i] * val[1] + val[2];
                float gy = bse[j] * val[3] + bse[i] * val[4] + val[5];
                float ax = (gx + 1.f + (float)ow2) * (2.f / 55.f) - 1.f;
                float ay = (gy + 1.f + (float)oh2) * (2.f / 55.f) - 1.f;
                int ij = i * 3 + j;
                o_ax[n * 9 + ij] = ax;
                o_ay[n * 9 + ij] = ay;
                sxy[(n * 9 + ij) * 2 + 0] = (ax + 1.f) * 28.f - 0.5f;
                sxy[(n * 9 + ij) * 2 + 1] = (ay + 1.f) * 28.f - 0.5f;
            }
    }
}

// ---- k_sgemm: round-1 proven version (fused bilinear-gather + GEMM, 64s x 128o) ----
__global__ __launch_bounds__(256) void k_sgemm(const unsigned short* __restrict__ xnh,
                                               const unsigned short* __restrict__ Wt,
                                               const float* __restrict__ bias,
                                               const float* __restrict__ sxy,
                                               float* __restrict__ score) {
    __shared__ unsigned short Ss[64 * LDP];    // samples (A-tile, gathered)
    __shared__ unsigned short Ws[128 * LDP];   // o-rows
    const int tid = threadIdx.x;
    const int lane = tid & 63, wid = tid >> 6;
    const int wr = wid >> 1, wc = wid & 1;
    const int o0 = blockIdx.x * 128;
    const int s0 = blockIdx.y * 64;

    f32x4 acc[4][2];
    #pragma unroll
    for (int mt = 0; mt < 4; mt++)
        #pragma unroll
        for (int nt = 0; nt < 2; nt++) { acc[mt][nt][0]=0.f; acc[mt][nt][1]=0.f; acc[mt][nt][2]=0.f; acc[mt][nt][3]=0.f; }

    // gather assignment: row = sample (64), q = ic-sixteenth (4)
    const int row = tid >> 2, q = tid & 3;
    const int mp = min(s0 + row, NN - 1);           // score-linear sample id
    const int b = mp / OPLANE; const int rr = mp - b * OPLANE;
    const int ho = rr / 54, wo = rr - (rr / 54) * 54;
    const int n = (b * 54 + wo) * 54 + ho;          // theta-order id (sxy index)
    const int xbase = b * PLANE;
    unsigned short* ssw = &Ss[row * LDP + q * 16];
    // weight staging: wrow = o-row (128), wq = half (2), 4 uint4 per thread
    const int wrow = tid >> 1, wq = tid & 1;
    const unsigned short* wg = Wt + (o0 + wrow) * KDIM + wq * 32;
    unsigned short* wsw = &Ws[wrow * LDP + wq * 32];
    const int lm = lane & 15, lq = lane >> 4;

    // hoist all 9 sample coordinates out of the K-loop
    float2 sc[9];
    {
        const float* spp = sxy + n * 18;
        #pragma unroll
        for (int ij = 0; ij < 9; ij++) sc[ij] = *(const float2*)(spp + ij * 2);
    }

    int off0 = 0, off1 = 0, off2 = 0, off3 = 0;
    float wt0 = 0.f, wt1 = 0.f, wt2 = 0.f, wt3 = 0.f;
    auto mkoff = [&](int ij) {
        float sx = sc[ij].x, sy = sc[ij].y;
        float x0f = floorf(sx), y0f = floorf(sy);
        float wx = sx - x0f, wy = sy - y0f;
        int x0 = (int)x0f, y0 = (int)y0f;
        int x1 = x0 + 1, y1 = y0 + 1;
        float vx0 = (x0 >= 0 && x0 < 56) ? 1.f : 0.f;
        float vx1 = (x1 >= 0 && x1 < 56) ? 1.f : 0.f;
        float vy0 = (y0 >= 0 && y0 < 56) ? 1.f : 0.f;
        float vy1 = (y1 >= 0 && y1 < 56) ? 1.f : 0.f;
        int xc0 = min(max(x0, 0), 55), xc1 = min(max(x1, 0), 55);
        int yc0 = min(max(y0, 0), 55), yc1 = min(max(y1, 0), 55);
        off0 = (xbase + yc0 * 56 + xc0) << 7;
        off1 = (xbase + yc0 * 56 + xc1) << 7;
        off2 = (xbase + yc1 * 56 + xc0) << 7;
        off3 = (xbase + yc1 * 56 + xc1) << 7;
        wt0 = vy0 * vx0 * (1.f - wx) * (1.f - wy);
        wt1 = vy0 * vx1 * wx * (1.f - wy);
        wt2 = vy1 * vx0 * (1.f - wx) * wy;
        wt3 = vy1 * vx1 * wx * wy;
    };

    uint4 p0a, p0b, p1a, p1b, p2a, p2b, p3a, p3b;
    uint4 w0v, w1v, w2v, w3v;
    auto issue = [&](int it) {
        const int co = ((it & 1) << 6) + q * 16;
        p0a = *(const uint4*)(xnh + off0 + co);
        p0b = *(const uint4*)(xnh + off0 + co + 8);
        p1a = *(const uint4*)(xnh + off1 + co);
        p1b = *(const uint4*)(xnh + off1 + co + 8);
        p2a = *(const uint4*)(xnh + off2 + co);
        p2b = *(const uint4*)(xnh + off2 + co + 8);
        p3a = *(const uint4*)(xnh + off3 + co);
        p3b = *(const uint4*)(xnh + off3 + co + 8);
        w0v = *(const uint4*)(wg + it * 64);
        w1v = *(const uint4*)(wg + it * 64 + 8);
        w2v = *(const uint4*)(wg + it * 64 + 16);
        w3v = *(const uint4*)(wg + it * 64 + 24);
    };

    mkoff(0);
    issue(0);

    #pragma unroll
    for (int it = 0; it < 18; it++) {
        // blend 16 lanes: v = wt0*p0 + wt1*p1 + wt2*p2 + wt3*p3 (fp32), pack bf16
        unsigned dw[8];
        const unsigned* d0 = (const unsigned*)&p0a;
        const unsigned* d1 = (const unsigned*)&p1a;
        const unsigned* d2 = (const unsigned*)&p2a;
        const unsigned* d3 = (const unsigned*)&p3a;
        const unsigned* e0 = (const unsigned*)&p0b;
        const unsigned* e1 = (const unsigned*)&p1b;
        const unsigned* e2 = (const unsigned*)&p2b;
        const unsigned* e3 = (const unsigned*)&p3b;
        #pragma unroll
        for (int d = 0; d < 8; d++) {
            unsigned u0 = (d < 4) ? d0[d] : e0[d - 4];
            unsigned u1 = (d < 4) ? d1[d] : e1[d - 4];
            unsigned u2 = (d < 4) ? d2[d] : e2[d - 4];
            unsigned u3 = (d < 4) ? d3[d] : e3[d - 4];
            float lo = wt0 * __builtin_bit_cast(float, u0 << 16)
                     + wt1 * __builtin_bit_cast(float, u1 << 16)
                     + wt2 * __builtin_bit_cast(float, u2 << 16)
                     + wt3 * __builtin_bit_cast(float, u3 << 16);
            float hi = wt0 * __builtin_bit_cast(float, u0 & 0xffff0000u)
                     + wt1 * __builtin_bit_cast(float, u1 & 0xffff0000u)
                     + wt2 * __builtin_bit_cast(float, u2 & 0xffff0000u)
                     + wt3 * __builtin_bit_cast(float, u3 & 0xffff0000u);
            dw[d] = (unsigned)f2bf(lo) | ((unsigned)f2bf(hi) << 16);
        }
        __syncthreads();                      // prev MFMA reads of LDS done
        *(uint4*)(ssw + 0) = *(uint4*)&dw[0];
        *(uint4*)(ssw + 8) = *(uint4*)&dw[4];
        *(uint4*)(wsw + 0)  = w0v;
        *(uint4*)(wsw + 8)  = w1v;
        *(uint4*)(wsw + 16) = w2v;
        *(uint4*)(wsw + 24) = w3v;
        __syncthreads();
        if (it < 17) {                        // prefetch next stage
            if (((it + 1) & 1) == 0) mkoff((it + 1) >> 1);
            issue(it + 1);
        }
        #pragma unroll
        for (int kk = 0; kk < 64; kk += 32) {
            bf16x8 wf[4], sf[2];
            #pragma unroll
            for (int mt = 0; mt < 4; mt++)
                wf[mt] = *(const bf16x8*)&Ws[(wr * 64 + mt * 16 + lm) * LDP + kk + lq * 8];
            #pragma unroll
            for (int nt = 0; nt < 2; nt++)
                sf[nt] = *(const bf16x8*)&Ss[(wc * 32 + nt * 16 + lm) * LDP + kk + lq * 8];
            #pragma unroll
            for (int mt = 0; mt < 4; mt++)
                #pragma unroll
                for (int nt = 0; nt < 2; nt++)
                    acc[mt][nt] = __builtin_amdgcn_mfma_f32_16x16x32_bf16(wf[mt], sf[nt], acc[mt][nt], 0, 0, 0);
        }
    }
    #pragma unroll
    for (int mt = 0; mt < 4; mt++) {
        #pragma unroll
        for (int r = 0; r < 4; r++) {
            int o = o0 + wr * 64 + mt * 16 + lq * 4 + r;
            float bb = bias[o];
            #pragma unroll
            for (int nt = 0; nt < 2; nt++) {
                int s = s0 + wc * 32 + nt * 16 + lm;
                if (s < NN) {
                    int sb = s / OPLANE;
                    int soff = s - sb * OPLANE;
                    score[(sb * 256 + o) * OPLANE + soff] = acc[mt][nt][r] + bb;
                }
            }
        }
    }
}

extern "C" void kernel_launch(void* const* d_in, const int* in_sizes, int n_in,
                              void* d_out, int out_size, void* d_ws, size_t ws_size,
                              hipStream_t stream) {
    const float* x  = (const float*)d_in[0];
    const float* w0 = (const float*)d_in[1];
    const float* b0 = (const float*)d_in[2];
    const float* w1 = (const float*)d_in[3];
    const float* lw = (const float*)d_in[4];
    const float* lb = (const float*)d_in[5];
    const int* check = (const int*)d_in[6];

    float* out   = (float*)d_out;
    float* score = out;                    // 8*256*54*54 = 5,971,968
    float* o_th  = out + 5971968;          // 139,968
    float* o_out = out + 6111936;          // 139,968
    float* o_ax  = out + 6251904;          // 209,952
    float* o_ay  = out + 6461856;          // 209,952

    char* wsb = (char*)d_ws;
    float* h   = (float*)wsb;                                    //  12,845,056 B
    unsigned short* xnh = (unsigned short*)(wsb + 12845056);     //   6,422,528 B
    unsigned short* b1t = (unsigned short*)(wsb + 19267584);     //     294,912 B
    unsigned short* b2t = (unsigned short*)(wsb + 19562496);     //     589,824 B
    float* sxy = (float*)(wsb + 20152320);                       //   1,679,616 B -> 21.8 MB total

    k_pre<<<2176, 256, 0, stream>>>(x, w0, lw, xnh, b1t, b2t);
    k_gemm1<<<392, 512, 0, stream>>>(xnh, b1t, b0, h);
    k_conv2f<<<1458, 256, 0, stream>>>(h, w1, check, o_out, o_th, o_ax, o_ay, sxy);
    k_sgemm<<<dim3(2, 365), 256, 0, stream>>>(xnh, b2t, lb, sxy, score);
}

// Round 10
// 161.658 us; speedup vs baseline: 1.2389x; 1.0331x over previous
//
#include <hip/hip_runtime.h>

typedef __attribute__((ext_vector_type(4))) float f32x4;
typedef __attribute__((ext_vector_type(8))) short bf16x8;

#define OPLANE 2916     // 54*54
#define NN 23328        // 8*54*54
#define KDIM 1152       // 128*9
#define PLANE 3136      // 56*56
#define LDP 72          // LDS row (shorts): 144B stride -> 2-way max alias (free)

__device__ __forceinline__ unsigned short f2bf(float f) {
    unsigned u = __builtin_bit_cast(unsigned, f);
    u += 0x7fffu + ((u >> 16) & 1u);
    return (unsigned short)(u >> 16);
}
__device__ __forceinline__ float bflo(unsigned u) {   // low bf16 of dword -> f32
    return __builtin_bit_cast(float, u << 16);
}
__device__ __forceinline__ float bfhi(unsigned u) {   // high bf16 of dword -> f32
    return __builtin_bit_cast(float, u & 0xffff0000u);
}

// ---- k_pre: fused {weights->bf16 K-permute} + {x NCHW fp32 -> NHWC bf16} ----
__global__ __launch_bounds__(256) void k_pre(const float* __restrict__ x,
                                             const float* __restrict__ w0,
                                             const float* __restrict__ lw,
                                             unsigned short* __restrict__ xnh,
                                             unsigned short* __restrict__ b1t,
                                             unsigned short* __restrict__ b2t) {
    __shared__ unsigned short lds[56 * 132];
    if (blockIdx.x < 1728) {
        int idx = blockIdx.x * 256 + threadIdx.x;   // 442368 = 147456 + 294912
        if (idx < 147456) {
            int r = idx / KDIM, k = idx - r * KDIM;
            int ij = k >> 7, ic = k & 127;
            b1t[idx] = f2bf(w0[r * KDIM + ic * 9 + ij]);
        } else {
            int j = idx - 147456;
            int r = j / KDIM, k = j - r * KDIM;
            int ij = k >> 7, ic = k & 127;
            b2t[j] = f2bf(lw[r * KDIM + ic * 9 + ij]);
        }
    } else {
        const int bid = blockIdx.x - 1728;
        const int y = bid % 56, b = bid / 56, tid = threadIdx.x;
        for (int i = tid; i < 7168; i += 256) {
            int ic = i / 56, xc = i - ic * 56;
            lds[xc * 132 + ic] = f2bf(x[(b * 128 + ic) * PLANE + y * 56 + xc]);
        }
        __syncthreads();
        for (int i = tid; i < 7168; i += 256) {
            int xc = i >> 7, ic = i & 127;
            xnh[(b * PLANE + y * 56 + xc) * 128 + ic] = lds[xc * 132 + ic];
        }
    }
}

// ---- gemm1 (fused im2col): h = relu(im2col(xnh) * b1t^T + b0), h stored BF16 ----
// n-merged: grid 392 x 512 threads, 64x128 tile, 8 waves of 32x32.
__global__ __launch_bounds__(512) void k_gemm1(const unsigned short* __restrict__ xnh,
                                               const unsigned short* __restrict__ Bt,
                                               const float* __restrict__ bias,
                                               unsigned short* __restrict__ h) {
    __shared__ unsigned short As[64 * LDP];
    __shared__ unsigned short Bs[128 * LDP];
    const int tid = threadIdx.x;
    const int lane = tid & 63, wid = tid >> 6;   // 8 waves
    const int wr = wid >> 2, wc = wid & 3;       // 2 m-halves x 4 n-quarters
    const int m0 = blockIdx.x * 64;              // 392 m-tiles

    f32x4 acc[2][2];
    #pragma unroll
    for (int mt = 0; mt < 2; mt++)
        #pragma unroll
        for (int nt = 0; nt < 2; nt++) { acc[mt][nt][0]=0.f; acc[mt][nt][1]=0.f; acc[mt][nt][2]=0.f; acc[mt][nt][3]=0.f; }

    // A staging: row = sample (64), 8 threads/row, 8 shorts (1 uint4) each
    const int row = tid >> 3, q = tid & 7;
    const int p = m0 + row;
    const int b = p / PLANE; int rem = p - b * PLANE;
    const int y = rem / 56; const int xc = rem - y * 56;
    unsigned short* asw = &As[row * LDP + q * 8];
    // B staging: 128 rows, 4 threads/row, 16 shorts (2 uint4) each
    const int brow = tid >> 2, bq = tid & 3;
    const unsigned short* bg = Bt + brow * KDIM + bq * 16;
    unsigned short* bsw = &Bs[brow * LDP + bq * 16];
    const int lm = lane & 15, lq = lane >> 4;

    uint4 a0, bv0, bv1;
    auto issue = [&](int it) {
        const int ij = it >> 1;
        const int di = ij / 3, dj = ij - di * 3;
        const int icb = (it & 1) << 6;
        a0 = make_uint4(0u,0u,0u,0u);
        bool valid = (y + di >= 1) && (y + di <= 56) && (xc + dj >= 1) && (xc + dj <= 56);
        if (valid) {
            const unsigned short* ap = xnh + (p + (di - 1) * 56 + (dj - 1)) * 128 + icb + q * 8;
            a0 = *(const uint4*)ap;
        }
        bv0 = *(const uint4*)(bg + it * 64);
        bv1 = *(const uint4*)(bg + it * 64 + 8);
    };
    issue(0);

    #pragma unroll
    for (int it = 0; it < 18; it++) {
        __syncthreads();
        *(uint4*)asw = a0;
        *(uint4*)(bsw + 0) = bv0; *(uint4*)(bsw + 8) = bv1;
        __syncthreads();
        if (it < 17) issue(it + 1);
        #pragma unroll
        for (int kk = 0; kk < 64; kk += 32) {
            bf16x8 af[2], bf[2];
            #pragma unroll
            for (int mt = 0; mt < 2; mt++)
                af[mt] = *(const bf16x8*)&As[(wr * 32 + mt * 16 + lm) * LDP + kk + lq * 8];
            #pragma unroll
            for (int nt = 0; nt < 2; nt++)
                bf[nt] = *(const bf16x8*)&Bs[(wc * 32 + nt * 16 + lm) * LDP + kk + lq * 8];
            #pragma unroll
            for (int mt = 0; mt < 2; mt++)
                #pragma unroll
                for (int nt = 0; nt < 2; nt++)
                    acc[mt][nt] = __builtin_amdgcn_mfma_f32_16x16x32_bf16(af[mt], bf[nt], acc[mt][nt], 0, 0, 0);
        }
    }
    #pragma unroll
    for (int mt = 0; mt < 2; mt++) {
        int m = m0 + wr * 32 + mt * 16 + lq * 4;
        #pragma unroll
        for (int nt = 0; nt < 2; nt++) {
            int n = wc * 32 + nt * 16 + lm;
            float bb = bias[n];
            #pragma unroll
            for (int r = 0; r < 4; r++)
                h[(m + r) * 128 + n] = f2bf(fmaxf(acc[mt][nt][r] + bb, 0.f));
        }
    }
}

// ---- k_conv2f: conv2 (NHWC bf16 h, LDS fp32 weights) + theta epilogue, fused ----
__global__ __launch_bounds__(256) void k_conv2f(const unsigned short* __restrict__ h,
                                                const float* __restrict__ w1,
                                                const int* __restrict__ check,
                                                float* __restrict__ o_out,
                                                float* __restrict__ o_th,
                                                float* __restrict__ o_ax,
                                                float* __restrict__ o_ay,
                                                float* __restrict__ sxy) {
    __shared__ float wlds[6912];        // [r][ij*128+ic]
    __shared__ float red[16 * 6 * 17];  // [pt][r][c] stride-17
    __shared__ float vals[96];
    const int tid = threadIdx.x;
    for (int idx = tid; idx < 6912; idx += 256) {
        int r = idx / KDIM, k = idx - r * KDIM;
        int ij = k >> 7, ic = k & 127;
        wlds[idx] = w1[r * KDIM + ic * 9 + ij];
    }
    __syncthreads();
    const int pt = tid >> 4, c = tid & 15;
    const int p = blockIdx.x * 16 + pt;
    int b = p / OPLANE; int rem = p - b * OPLANE; int oh = rem / 54; int ow = rem - oh * 54;
    const uint4* h4 = (const uint4*)h;          // 8 bf16 channels per uint4
    const float4* w4 = (const float4*)wlds;
    float acc[6] = {0.f, 0.f, 0.f, 0.f, 0.f, 0.f};
    const int base_sp = b * PLANE + oh * 56 + ow;
    #pragma unroll
    for (int i = 0; i < 3; i++) {
        #pragma unroll
        for (int j = 0; j < 3; j++) {
            int sp = base_sp + i * 56 + j;
            uint4 hu = h4[sp * 16 + c];         // ch c*8 .. c*8+7 (bf16 pairs)
            float f0 = bflo(hu.x), f1 = bfhi(hu.x);
            float f2 = bflo(hu.y), f3 = bfhi(hu.y);
            float f4 = bflo(hu.z), f5 = bfhi(hu.z);
            float f6 = bflo(hu.w), f7 = bfhi(hu.w);
            int ij = i * 3 + j;
            #pragma unroll
            for (int r = 0; r < 6; r++) {
                float4 wa = w4[r * 288 + ij * 32 + c * 2];
                float4 wb = w4[r * 288 + ij * 32 + c * 2 + 1];
                acc[r] += f0 * wa.x + f1 * wa.y + f2 * wa.z + f3 * wa.w
                        + f4 * wb.x + f5 * wb.y + f6 * wb.z + f7 * wb.w;
            }
        }
    }
    #pragma unroll
    for (int r = 0; r < 6; r++) red[(pt * 6 + r) * 17 + c] = acc[r];
    __syncthreads();
    if (tid < 96) {
        const float* rp = &red[tid * 17];
        float s = 0.f;
        #pragma unroll
        for (int e = 0; e < 16; e++) s += rp[e];
        vals[tid] = s;
    }
    __syncthreads();
    if (tid < 16) {
        int p2 = blockIdx.x * 16 + tid;
        int b2 = p2 / OPLANE; int r2 = p2 - b2 * OPLANE; int oh2 = r2 / 54; int ow2 = r2 - oh2 * 54;
        float val[6];
        float s = 1.0f - (float)check[0];
        const float id6[6] = {1.f, 0.f, 0.f, 0.f, 1.f, 0.f};
        #pragma unroll
        for (int r = 0; r < 6; r++) val[r] = vals[tid * 6 + r] * s + id6[r];
        int n = (b2 * 54 + ow2) * 54 + oh2;
        #pragma unroll
        for (int r = 0; r < 6; r++) {
            o_out[((b2 * 6 + r) * 54 + oh2) * 54 + ow2] = val[r];
            o_th[n * 6 + r] = id6[r] - val[r];
        }
        const float bse[3] = {-2.f / 3.f, 0.f, 2.f / 3.f};
        #pragma unroll
        for (int i = 0; i < 3; i++)
            #pragma unroll
            for (int j = 0; j < 3; j++) {
                float gx = bse[j] * val[0] + bse[i] * val[1] + val[2];
                float gy = bse[j] * val[3] + bse[i] * val[4] + val[5];
                float ax = (gx + 1.f + (float)ow2) * (2.f / 55.f) - 1.f;
                float ay = (gy + 1.f + (float)oh2) * (2.f / 55.f) - 1.f;
                int ij = i * 3 + j;
                o_ax[n * 9 + ij] = ax;
                o_ay[n * 9 + ij] = ay;
                sxy[(n * 9 + ij) * 2 + 0] = (ax + 1.f) * 28.f - 0.5f;
                sxy[(n * 9 + ij) * 2 + 1] = (ay + 1.f) * 28.f - 0.5f;
            }
    }
}

// ---- k_sgemm: proven 64s x 128o structure + XCD pair-colocation swizzle ----
// Blocks (o-half 0, s) and (o-half 1, s) issue identical gathers; remap the 1D
// dispatch index so both land on the SAME XCD (i%8 equal) -> second member's
// gathers hit XCD-local L2 instead of L3. Grid 736 = 46 groups x 16; p>=365 idles.
__global__ __launch_bounds__(256) void k_sgemm(const unsigned short* __restrict__ xnh,
                                               const unsigned short* __restrict__ Wt,
                                               const float* __restrict__ bias,
                                               const float* __restrict__ sxy,
                                               float* __restrict__ score) {
    __shared__ unsigned short Ss[64 * LDP];    // samples (A-tile, gathered)
    __shared__ unsigned short Ws[128 * LDP];   // o-rows
    const int i = blockIdx.x;
    const int g = i >> 4, r16 = i & 15;
    const int m8 = r16 >> 3;                   // o-half
    const int pp = g * 8 + (r16 & 7);          // sample-tile id; i%8 == pp%8 for both halves
    if (pp >= 365) return;                     // uniform per-block
    const int o0 = m8 * 128;
    const int s0 = pp * 64;
    const int tid = threadIdx.x;
    const int lane = tid & 63, wid = tid >> 6;
    const int wr = wid >> 1, wc = wid & 1;

    f32x4 acc[4][2];
    #pragma unroll
    for (int mt = 0; mt < 4; mt++)
        #pragma unroll
        for (int nt = 0; nt < 2; nt++) { acc[mt][nt][0]=0.f; acc[mt][nt][1]=0.f; acc[mt][nt][2]=0.f; acc[mt][nt][3]=0.f; }

    // gather assignment: row = sample (64), q = ic-sixteenth (4)
    const int row = tid >> 2, q = tid & 3;
    const int mp = min(s0 + row, NN - 1);           // score-linear sample id
    const int b = mp / OPLANE; const int rr = mp - b * OPLANE;
    const int ho = rr / 54, wo = rr - (rr / 54) * 54;
    const int n = (b * 54 + wo) * 54 + ho;          // theta-order id (sxy index)
    const int xbase = b * PLANE;
    unsigned short* ssw = &Ss[row * LDP + q * 16];
    // weight staging: wrow = o-row (128), wq = half (2), 4 uint4 per thread
    const int wrow = tid >> 1, wq = tid & 1;
    const unsigned short* wg = Wt + (o0 + wrow) * KDIM + wq * 32;
    unsigned short* wsw = &Ws[wrow * LDP + wq * 32];
    const int lm = lane & 15, lq = lane >> 4;

    // hoist all 9 sample coordinates out of the K-loop
    float2 sc[9];
    {
        const float* spp = sxy + n * 18;
        #pragma unroll
        for (int ij = 0; ij < 9; ij++) sc[ij] = *(const float2*)(spp + ij * 2);
    }

    int off0 = 0, off1 = 0, off2 = 0, off3 = 0;
    float wt0 = 0.f, wt1 = 0.f, wt2 = 0.f, wt3 = 0.f;
    auto mkoff = [&](int ij) {
        float sx = sc[ij].x, sy = sc[ij].y;
        float x0f = floorf(sx), y0f = floorf(sy);
        float wx = sx - x0f, wy = sy - y0f;
        int x0 = (int)x0f, y0 = (int)y0f;
        int x1 = x0 + 1, y1 = y0 + 1;
        float vx0 = (x0 >= 0 && x0 < 56) ? 1.f : 0.f;
        float vx1 = (x1 >= 0 && x1 < 56) ? 1.f : 0.f;
        float vy0 = (y0 >= 0 && y0 < 56) ? 1.f : 0.f;
        float vy1 = (y1 >= 0 && y1 < 56) ? 1.f : 0.f;
        int xc0 = min(max(x0, 0), 55), xc1 = min(max(x1, 0), 55);
        int yc0 = min(max(y0, 0), 55), yc1 = min(max(y1, 0), 55);
        off0 = (xbase + yc0 * 56 + xc0) << 7;
        off1 = (xbase + yc0 * 56 + xc1) << 7;
        off2 = (xbase + yc1 * 56 + xc0) << 7;
        off3 = (xbase + yc1 * 56 + xc1) << 7;
        wt0 = vy0 * vx0 * (1.f - wx) * (1.f - wy);
        wt1 = vy0 * vx1 * wx * (1.f - wy);
        wt2 = vy1 * vx0 * (1.f - wx) * wy;
        wt3 = vy1 * vx1 * wx * wy;
    };

    uint4 p0a, p0b, p1a, p1b, p2a, p2b, p3a, p3b;
    uint4 w0v, w1v, w2v, w3v;
    auto issue = [&](int it) {
        const int co = ((it & 1) << 6) + q * 16;
        p0a = *(const uint4*)(xnh + off0 + co);
        p0b = *(const uint4*)(xnh + off0 + co + 8);
        p1a = *(const uint4*)(xnh + off1 + co);
        p1b = *(const uint4*)(xnh + off1 + co + 8);
        p2a = *(const uint4*)(xnh + off2 + co);
        p2b = *(const uint4*)(xnh + off2 + co + 8);
        p3a = *(const uint4*)(xnh + off3 + co);
        p3b = *(const uint4*)(xnh + off3 + co + 8);
        w0v = *(const uint4*)(wg + it * 64);
        w1v = *(const uint4*)(wg + it * 64 + 8);
        w2v = *(const uint4*)(wg + it * 64 + 16);
        w3v = *(const uint4*)(wg + it * 64 + 24);
    };

    mkoff(0);
    issue(0);

    #pragma unroll
    for (int it = 0; it < 18; it++) {
        // blend 16 lanes: v = wt0*p0 + wt1*p1 + wt2*p2 + wt3*p3 (fp32), pack bf16
        unsigned dw[8];
        const unsigned* d0 = (const unsigned*)&p0a;
        const unsigned* d1 = (const unsigned*)&p1a;
        const unsigned* d2 = (const unsigned*)&p2a;
        const unsigned* d3 = (const unsigned*)&p3a;
        const unsigned* e0 = (const unsigned*)&p0b;
        const unsigned* e1 = (const unsigned*)&p1b;
        const unsigned* e2 = (const unsigned*)&p2b;
        const unsigned* e3 = (const unsigned*)&p3b;
        #pragma unroll
        for (int d = 0; d < 8; d++) {
            unsigned u0 = (d < 4) ? d0[d] : e0[d - 4];
            unsigned u1 = (d < 4) ? d1[d] : e1[d - 4];
            unsigned u2 = (d < 4) ? d2[d] : e2[d - 4];
            unsigned u3 = (d < 4) ? d3[d] : e3[d - 4];
            float lo = wt0 * bflo(u0) + wt1 * bflo(u1) + wt2 * bflo(u2) + wt3 * bflo(u3);
            float hi = wt0 * bfhi(u0) + wt1 * bfhi(u1) + wt2 * bfhi(u2) + wt3 * bfhi(u3);
            dw[d] = (unsigned)f2bf(lo) | ((unsigned)f2bf(hi) << 16);
        }
        __syncthreads();                      // prev MFMA reads of LDS done
        *(uint4*)(ssw + 0) = *(uint4*)&dw[0];
        *(uint4*)(ssw + 8) = *(uint4*)&dw[4];
        *(uint4*)(wsw + 0)  = w0v;
        *(uint4*)(wsw + 8)  = w1v;
        *(uint4*)(wsw + 16) = w2v;
        *(uint4*)(wsw + 24) = w3v;
        __syncthreads();
        if (it < 17) {                        // prefetch next stage
            if (((it + 1) & 1) == 0) mkoff((it + 1) >> 1);
            issue(it + 1);
        }
        #pragma unroll
        for (int kk = 0; kk < 64; kk += 32) {
            bf16x8 wf[4], sf[2];
            #pragma unroll
            for (int mt = 0; mt < 4; mt++)
                wf[mt] = *(const bf16x8*)&Ws[(wr * 64 + mt * 16 + lm) * LDP + kk + lq * 8];
            #pragma unroll
            for (int nt = 0; nt < 2; nt++)
                sf[nt] = *(const bf16x8*)&Ss[(wc * 32 + nt * 16 + lm) * LDP + kk + lq * 8];
            #pragma unroll
            for (int mt = 0; mt < 4; mt++)
                #pragma unroll
                for (int nt = 0; nt < 2; nt++)
                    acc[mt][nt] = __builtin_amdgcn_mfma_f32_16x16x32_bf16(wf[mt], sf[nt], acc[mt][nt], 0, 0, 0);
        }
    }
    #pragma unroll
    for (int mt = 0; mt < 4; mt++) {
        #pragma unroll
        for (int r = 0; r < 4; r++) {
            int o = o0 + wr * 64 + mt * 16 + lq * 4 + r;
            float bb = bias[o];
            #pragma unroll
            for (int nt = 0; nt < 2; nt++) {
                int s = s0 + wc * 32 + nt * 16 + lm;
                if (s < NN) {
                    int sb = s / OPLANE;
                    int soff = s - sb * OPLANE;
                    score[(sb * 256 + o) * OPLANE + soff] = acc[mt][nt][r] + bb;
                }
            }
        }
    }
}

extern "C" void kernel_launch(void* const* d_in, const int* in_sizes, int n_in,
                              void* d_out, int out_size, void* d_ws, size_t ws_size,
                              hipStream_t stream) {
    const float* x  = (const float*)d_in[0];
    const float* w0 = (const float*)d_in[1];
    const float* b0 = (const float*)d_in[2];
    const float* w1 = (const float*)d_in[3];
    const float* lw = (const float*)d_in[4];
    const float* lb = (const float*)d_in[5];
    const int* check = (const int*)d_in[6];

    float* out   = (float*)d_out;
    float* score = out;                    // 8*256*54*54 = 5,971,968
    float* o_th  = out + 5971968;          // 139,968
    float* o_out = out + 6111936;          // 139,968
    float* o_ax  = out + 6251904;          // 209,952
    float* o_ay  = out + 6461856;          // 209,952

    char* wsb = (char*)d_ws;
    unsigned short* h   = (unsigned short*)wsb;                  //   6,422,528 B (bf16 now)
    unsigned short* xnh = (unsigned short*)(wsb + 12845056);     //   6,422,528 B
    unsigned short* b1t = (unsigned short*)(wsb + 19267584);     //     294,912 B
    unsigned short* b2t = (unsigned short*)(wsb + 19562496);     //     589,824 B
    float* sxy = (float*)(wsb + 20152320);                       //   1,679,616 B -> 21.8 MB total

    k_pre<<<2176, 256, 0, stream>>>(x, w0, lw, xnh, b1t, b2t);
    k_gemm1<<<392, 512, 0, stream>>>(xnh, b1t, b0, h);
    k_conv2f<<<1458, 256, 0, stream>>>(h, w1, check, o_out, o_th, o_ax, o_ay, sxy);
    k_sgemm<<<736, 256, 0, stream>>>(xnh, b2t, lb, sxy, score);
}

// Round 11
// 161.006 us; speedup vs baseline: 1.2439x; 1.0041x over previous
//
#include <hip/hip_runtime.h>

typedef __attribute__((ext_vector_type(4))) float f32x4;
typedef __attribute__((ext_vector_type(8))) short bf16x8;

#define OPLANE 2916     // 54*54
#define NN 23328        // 8*54*54
#define KDIM 1152       // 128*9
#define PLANE 3136      // 56*56
#define LDP 72          // LDS row (shorts): 144B stride -> 2-way max alias (free)

__device__ __forceinline__ unsigned short f2bf(float f) {
    unsigned u = __builtin_bit_cast(unsigned, f);
    u += 0x7fffu + ((u >> 16) & 1u);
    return (unsigned short)(u >> 16);
}
__device__ __forceinline__ float bflo(unsigned u) {   // low bf16 of dword -> f32
    return __builtin_bit_cast(float, u << 16);
}
__device__ __forceinline__ float bfhi(unsigned u) {   // high bf16 of dword -> f32
    return __builtin_bit_cast(float, u & 0xffff0000u);
}

// ---- k_pre: fused {weights->bf16 K-permute} + {x NCHW fp32 -> NHWC bf16} ----
__global__ __launch_bounds__(256) void k_pre(const float* __restrict__ x,
                                             const float* __restrict__ w0,
                                             const float* __restrict__ lw,
                                             unsigned short* __restrict__ xnh,
                                             unsigned short* __restrict__ b1t,
                                             unsigned short* __restrict__ b2t) {
    __shared__ unsigned short lds[56 * 132];
    if (blockIdx.x < 1728) {
        int idx = blockIdx.x * 256 + threadIdx.x;   // 442368 = 147456 + 294912
        if (idx < 147456) {
            int r = idx / KDIM, k = idx - r * KDIM;
            int ij = k >> 7, ic = k & 127;
            b1t[idx] = f2bf(w0[r * KDIM + ic * 9 + ij]);
        } else {
            int j = idx - 147456;
            int r = j / KDIM, k = j - r * KDIM;
            int ij = k >> 7, ic = k & 127;
            b2t[j] = f2bf(lw[r * KDIM + ic * 9 + ij]);
        }
    } else {
        const int bid = blockIdx.x - 1728;
        const int y = bid % 56, b = bid / 56, tid = threadIdx.x;
        for (int i = tid; i < 7168; i += 256) {
            int ic = i / 56, xc = i - ic * 56;
            lds[xc * 132 + ic] = f2bf(x[(b * 128 + ic) * PLANE + y * 56 + xc]);
        }
        __syncthreads();
        for (int i = tid; i < 7168; i += 256) {
            int xc = i >> 7, ic = i & 127;
            xnh[(b * PLANE + y * 56 + xc) * 128 + ic] = lds[xc * 132 + ic];
        }
    }
}

// ---- gemm1 (fused im2col): h = relu(im2col(xnh) * b1t^T + b0), h stored BF16 ----
// XCD-chunked m-tiles: 392 = 8 x 49; 49 m-tiles = 3136 samples = exactly one
// batch image per XCD -> A-slice (0.8 MB) + all of B (295 KB) L2-resident.
__global__ __launch_bounds__(512) void k_gemm1(const unsigned short* __restrict__ xnh,
                                               const unsigned short* __restrict__ Bt,
                                               const float* __restrict__ bias,
                                               unsigned short* __restrict__ h) {
    __shared__ unsigned short As[64 * LDP];
    __shared__ unsigned short Bs[128 * LDP];
    const int tid = threadIdx.x;
    const int lane = tid & 63, wid = tid >> 6;   // 8 waves
    const int wr = wid >> 2, wc = wid & 3;       // 2 m-halves x 4 n-quarters
    const int mt_id = (blockIdx.x & 7) * 49 + (blockIdx.x >> 3);  // chunked remap
    const int m0 = mt_id * 64;

    f32x4 acc[2][2];
    #pragma unroll
    for (int mt = 0; mt < 2; mt++)
        #pragma unroll
        for (int nt = 0; nt < 2; nt++) { acc[mt][nt][0]=0.f; acc[mt][nt][1]=0.f; acc[mt][nt][2]=0.f; acc[mt][nt][3]=0.f; }

    // A staging: row = sample (64), 8 threads/row, 8 shorts (1 uint4) each
    const int row = tid >> 3, q = tid & 7;
    const int p = m0 + row;
    const int b = p / PLANE; int rem = p - b * PLANE;
    const int y = rem / 56; const int xc = rem - y * 56;
    unsigned short* asw = &As[row * LDP + q * 8];
    // B staging: 128 rows, 4 threads/row, 16 shorts (2 uint4) each
    const int brow = tid >> 2, bq = tid & 3;
    const unsigned short* bg = Bt + brow * KDIM + bq * 16;
    unsigned short* bsw = &Bs[brow * LDP + bq * 16];
    const int lm = lane & 15, lq = lane >> 4;

    uint4 a0, bv0, bv1;
    auto issue = [&](int it) {
        const int ij = it >> 1;
        const int di = ij / 3, dj = ij - di * 3;
        const int icb = (it & 1) << 6;
        a0 = make_uint4(0u,0u,0u,0u);
        bool valid = (y + di >= 1) && (y + di <= 56) && (xc + dj >= 1) && (xc + dj <= 56);
        if (valid) {
            const unsigned short* ap = xnh + (p + (di - 1) * 56 + (dj - 1)) * 128 + icb + q * 8;
            a0 = *(const uint4*)ap;
        }
        bv0 = *(const uint4*)(bg + it * 64);
        bv1 = *(const uint4*)(bg + it * 64 + 8);
    };
    issue(0);

    #pragma unroll
    for (int it = 0; it < 18; it++) {
        __syncthreads();
        *(uint4*)asw = a0;
        *(uint4*)(bsw + 0) = bv0; *(uint4*)(bsw + 8) = bv1;
        __syncthreads();
        if (it < 17) issue(it + 1);
        #pragma unroll
        for (int kk = 0; kk < 64; kk += 32) {
            bf16x8 af[2], bf[2];
            #pragma unroll
            for (int mt = 0; mt < 2; mt++)
                af[mt] = *(const bf16x8*)&As[(wr * 32 + mt * 16 + lm) * LDP + kk + lq * 8];
            #pragma unroll
            for (int nt = 0; nt < 2; nt++)
                bf[nt] = *(const bf16x8*)&Bs[(wc * 32 + nt * 16 + lm) * LDP + kk + lq * 8];
            #pragma unroll
            for (int mt = 0; mt < 2; mt++)
                #pragma unroll
                for (int nt = 0; nt < 2; nt++)
                    acc[mt][nt] = __builtin_amdgcn_mfma_f32_16x16x32_bf16(af[mt], bf[nt], acc[mt][nt], 0, 0, 0);
        }
    }
    #pragma unroll
    for (int mt = 0; mt < 2; mt++) {
        int m = m0 + wr * 32 + mt * 16 + lq * 4;
        #pragma unroll
        for (int nt = 0; nt < 2; nt++) {
            int n = wc * 32 + nt * 16 + lm;
            float bb = bias[n];
            #pragma unroll
            for (int r = 0; r < 4; r++)
                h[(m + r) * 128 + n] = f2bf(fmaxf(acc[mt][nt][r] + bb, 0.f));
        }
    }
}

// ---- k_conv2f: conv2 (NHWC bf16 h, LDS fp32 weights) + theta epilogue, fused ----
// XCD-chunked: grid 1464 = 8 x 183 (6 idle); each XCD reads a 0.8 MB h-slice
// 9x from its own L2 instead of L3.
__global__ __launch_bounds__(256) void k_conv2f(const unsigned short* __restrict__ h,
                                                const float* __restrict__ w1,
                                                const int* __restrict__ check,
                                                float* __restrict__ o_out,
                                                float* __restrict__ o_th,
                                                float* __restrict__ o_ax,
                                                float* __restrict__ o_ay,
                                                float* __restrict__ sxy) {
    __shared__ float wlds[6912];        // [r][ij*128+ic]
    __shared__ float red[16 * 6 * 17];  // [pt][r][c] stride-17
    __shared__ float vals[96];
    const int bid = (blockIdx.x & 7) * 183 + (blockIdx.x >> 3);   // chunked remap
    if (bid >= 1458) return;            // uniform early-out, before any barrier
    const int tid = threadIdx.x;
    for (int idx = tid; idx < 6912; idx += 256) {
        int r = idx / KDIM, k = idx - r * KDIM;
        int ij = k >> 7, ic = k & 127;
        wlds[idx] = w1[r * KDIM + ic * 9 + ij];
    }
    __syncthreads();
    const int pt = tid >> 4, c = tid & 15;
    const int p = bid * 16 + pt;
    int b = p / OPLANE; int rem = p - b * OPLANE; int oh = rem / 54; int ow = rem - oh * 54;
    const uint4* h4 = (const uint4*)h;          // 8 bf16 channels per uint4
    const float4* w4 = (const float4*)wlds;
    float acc[6] = {0.f, 0.f, 0.f, 0.f, 0.f, 0.f};
    const int base_sp = b * PLANE + oh * 56 + ow;
    #pragma unroll
    for (int i = 0; i < 3; i++) {
        #pragma unroll
        for (int j = 0; j < 3; j++) {
            int sp = base_sp + i * 56 + j;
            uint4 hu = h4[sp * 16 + c];         // ch c*8 .. c*8+7 (bf16 pairs)
            float f0 = bflo(hu.x), f1 = bfhi(hu.x);
            float f2 = bflo(hu.y), f3 = bfhi(hu.y);
            float f4 = bflo(hu.z), f5 = bfhi(hu.z);
            float f6 = bflo(hu.w), f7 = bfhi(hu.w);
            int ij = i * 3 + j;
            #pragma unroll
            for (int r = 0; r < 6; r++) {
                float4 wa = w4[r * 288 + ij * 32 + c * 2];
                float4 wb = w4[r * 288 + ij * 32 + c * 2 + 1];
                acc[r] += f0 * wa.x + f1 * wa.y + f2 * wa.z + f3 * wa.w
                        + f4 * wb.x + f5 * wb.y + f6 * wb.z + f7 * wb.w;
            }
        }
    }
    #pragma unroll
    for (int r = 0; r < 6; r++) red[(pt * 6 + r) * 17 + c] = acc[r];
    __syncthreads();
    if (tid < 96) {
        const float* rp = &red[tid * 17];
        float s = 0.f;
        #pragma unroll
        for (int e = 0; e < 16; e++) s += rp[e];
        vals[tid] = s;
    }
    __syncthreads();
    if (tid < 16) {
        int p2 = bid * 16 + tid;
        int b2 = p2 / OPLANE; int r2 = p2 - b2 * OPLANE; int oh2 = r2 / 54; int ow2 = r2 - oh2 * 54;
        float val[6];
        float s = 1.0f - (float)check[0];
        const float id6[6] = {1.f, 0.f, 0.f, 0.f, 1.f, 0.f};
        #pragma unroll
        for (int r = 0; r < 6; r++) val[r] = vals[tid * 6 + r] * s + id6[r];
        int n = (b2 * 54 + ow2) * 54 + oh2;
        #pragma unroll
        for (int r = 0; r < 6; r++) {
            o_out[((b2 * 6 + r) * 54 + oh2) * 54 + ow2] = val[r];
            o_th[n * 6 + r] = id6[r] - val[r];
        }
        const float bse[3] = {-2.f / 3.f, 0.f, 2.f / 3.f};
        #pragma unroll
        for (int i = 0; i < 3; i++)
            #pragma unroll
            for (int j = 0; j < 3; j++) {
                float gx = bse[j] * val[0] + bse[i] * val[1] + val[2];
                float gy = bse[j] * val[3] + bse[i] * val[4] + val[5];
                float ax = (gx + 1.f + (float)ow2) * (2.f / 55.f) - 1.f;
                float ay = (gy + 1.f + (float)oh2) * (2.f / 55.f) - 1.f;
                int ij = i * 3 + j;
                o_ax[n * 9 + ij] = ax;
                o_ay[n * 9 + ij] = ay;
                sxy[(n * 9 + ij) * 2 + 0] = (ax + 1.f) * 28.f - 0.5f;
                sxy[(n * 9 + ij) * 2 + 1] = (ay + 1.f) * 28.f - 0.5f;
            }
    }
}

// ---- k_sgemm: proven 64s x 128o structure + XCD CHUNKED swizzle ----
// Each XCD owns 46 contiguous s-tiles x both o-halves: pair property (round-10,
// FETCH-confirmed) preserved, plus neighbor s-tiles' overlapping gather regions
// now share the same XCD L2. Grid 736 = 8 x 92; pp>=365 idles (6 blocks).
__global__ __launch_bounds__(256) void k_sgemm(const unsigned short* __restrict__ xnh,
                                               const unsigned short* __restrict__ Wt,
                                               const float* __restrict__ bias,
                                               const float* __restrict__ sxy,
                                               float* __restrict__ score) {
    __shared__ unsigned short Ss[64 * LDP];    // samples (A-tile, gathered)
    __shared__ unsigned short Ws[128 * LDP];   // o-rows
    const int i = blockIdx.x;
    const int xcd = i & 7, j = i >> 3;         // j in [0,92)
    const int pp = xcd * 46 + (j >> 1);        // 46 contiguous s-tiles per XCD
    const int m8 = j & 1;                      // o-half (pair member, same XCD)
    if (pp >= 365) return;                     // uniform per-block
    const int o0 = m8 * 128;
    const int s0 = pp * 64;
    const int tid = threadIdx.x;
    const int lane = tid & 63, wid = tid >> 6;
    const int wr = wid >> 1, wc = wid & 1;

    f32x4 acc[4][2];
    #pragma unroll
    for (int mt = 0; mt < 4; mt++)
        #pragma unroll
        for (int nt = 0; nt < 2; nt++) { acc[mt][nt][0]=0.f; acc[mt][nt][1]=0.f; acc[mt][nt][2]=0.f; acc[mt][nt][3]=0.f; }

    // gather assignment: row = sample (64), q = ic-sixteenth (4)
    const int row = tid >> 2, q = tid & 3;
    const int mp = min(s0 + row, NN - 1);           // score-linear sample id
    const int b = mp / OPLANE; const int rr = mp - b * OPLANE;
    const int ho = rr / 54, wo = rr - (rr / 54) * 54;
    const int n = (b * 54 + wo) * 54 + ho;          // theta-order id (sxy index)
    const int xbase = b * PLANE;
    unsigned short* ssw = &Ss[row * LDP + q * 16];
    // weight staging: wrow = o-row (128), wq = half (2), 4 uint4 per thread
    const int wrow = tid >> 1, wq = tid & 1;
    const unsigned short* wg = Wt + (o0 + wrow) * KDIM + wq * 32;
    unsigned short* wsw = &Ws[wrow * LDP + wq * 32];
    const int lm = lane & 15, lq = lane >> 4;

    // hoist all 9 sample coordinates out of the K-loop
    float2 sc[9];
    {
        const float* spp = sxy + n * 18;
        #pragma unroll
        for (int ij = 0; ij < 9; ij++) sc[ij] = *(const float2*)(spp + ij * 2);
    }

    int off0 = 0, off1 = 0, off2 = 0, off3 = 0;
    float wt0 = 0.f, wt1 = 0.f, wt2 = 0.f, wt3 = 0.f;
    auto mkoff = [&](int ij) {
        float sx = sc[ij].x, sy = sc[ij].y;
        float x0f = floorf(sx), y0f = floorf(sy);
        float wx = sx - x0f, wy = sy - y0f;
        int x0 = (int)x0f, y0 = (int)y0f;
        int x1 = x0 + 1, y1 = y0 + 1;
        float vx0 = (x0 >= 0 && x0 < 56) ? 1.f : 0.f;
        float vx1 = (x1 >= 0 && x1 < 56) ? 1.f : 0.f;
        float vy0 = (y0 >= 0 && y0 < 56) ? 1.f : 0.f;
        float vy1 = (y1 >= 0 && y1 < 56) ? 1.f : 0.f;
        int xc0 = min(max(x0, 0), 55), xc1 = min(max(x1, 0), 55);
        int yc0 = min(max(y0, 0), 55), yc1 = min(max(y1, 0), 55);
        off0 = (xbase + yc0 * 56 + xc0) << 7;
        off1 = (xbase + yc0 * 56 + xc1) << 7;
        off2 = (xbase + yc1 * 56 + xc0) << 7;
        off3 = (xbase + yc1 * 56 + xc1) << 7;
        wt0 = vy0 * vx0 * (1.f - wx) * (1.f - wy);
        wt1 = vy0 * vx1 * wx * (1.f - wy);
        wt2 = vy1 * vx0 * (1.f - wx) * wy;
        wt3 = vy1 * vx1 * wx * wy;
    };

    uint4 p0a, p0b, p1a, p1b, p2a, p2b, p3a, p3b;
    uint4 w0v, w1v, w2v, w3v;
    auto issue = [&](int it) {
        const int co = ((it & 1) << 6) + q * 16;
        p0a = *(const uint4*)(xnh + off0 + co);
        p0b = *(const uint4*)(xnh + off0 + co + 8);
        p1a = *(const uint4*)(xnh + off1 + co);
        p1b = *(const uint4*)(xnh + off1 + co + 8);
        p2a = *(const uint4*)(xnh + off2 + co);
        p2b = *(const uint4*)(xnh + off2 + co + 8);
        p3a = *(const uint4*)(xnh + off3 + co);
        p3b = *(const uint4*)(xnh + off3 + co + 8);
        w0v = *(const uint4*)(wg + it * 64);
        w1v = *(const uint4*)(wg + it * 64 + 8);
        w2v = *(const uint4*)(wg + it * 64 + 16);
        w3v = *(const uint4*)(wg + it * 64 + 24);
    };

    mkoff(0);
    issue(0);

    #pragma unroll
    for (int it = 0; it < 18; it++) {
        // blend 16 lanes: v = wt0*p0 + wt1*p1 + wt2*p2 + wt3*p3 (fp32), pack bf16
        unsigned dw[8];
        const unsigned* d0 = (const unsigned*)&p0a;
        const unsigned* d1 = (const unsigned*)&p1a;
        const unsigned* d2 = (const unsigned*)&p2a;
        const unsigned* d3 = (const unsigned*)&p3a;
        const unsigned* e0 = (const unsigned*)&p0b;
        const unsigned* e1 = (const unsigned*)&p1b;
        const unsigned* e2 = (const unsigned*)&p2b;
        const unsigned* e3 = (const unsigned*)&p3b;
        #pragma unroll
        for (int d = 0; d < 8; d++) {
            unsigned u0 = (d < 4) ? d0[d] : e0[d - 4];
            unsigned u1 = (d < 4) ? d1[d] : e1[d - 4];
            unsigned u2 = (d < 4) ? d2[d] : e2[d - 4];
            unsigned u3 = (d < 4) ? d3[d] : e3[d - 4];
            float lo = wt0 * bflo(u0) + wt1 * bflo(u1) + wt2 * bflo(u2) + wt3 * bflo(u3);
            float hi = wt0 * bfhi(u0) + wt1 * bfhi(u1) + wt2 * bfhi(u2) + wt3 * bfhi(u3);
            dw[d] = (unsigned)f2bf(lo) | ((unsigned)f2bf(hi) << 16);
        }
        __syncthreads();                      // prev MFMA reads of LDS done
        *(uint4*)(ssw + 0) = *(uint4*)&dw[0];
        *(uint4*)(ssw + 8) = *(uint4*)&dw[4];
        *(uint4*)(wsw + 0)  = w0v;
        *(uint4*)(wsw + 8)  = w1v;
        *(uint4*)(wsw + 16) = w2v;
        *(uint4*)(wsw + 24) = w3v;
        __syncthreads();
        if (it < 17) {                        // prefetch next stage
            if (((it + 1) & 1) == 0) mkoff((it + 1) >> 1);
            issue(it + 1);
        }
        #pragma unroll
        for (int kk = 0; kk < 64; kk += 32) {
            bf16x8 wf[4], sf[2];
            #pragma unroll
            for (int mt = 0; mt < 4; mt++)
                wf[mt] = *(const bf16x8*)&Ws[(wr * 64 + mt * 16 + lm) * LDP + kk + lq * 8];
            #pragma unroll
            for (int nt = 0; nt < 2; nt++)
                sf[nt] = *(const bf16x8*)&Ss[(wc * 32 + nt * 16 + lm) * LDP + kk + lq * 8];
            #pragma unroll
            for (int mt = 0; mt < 4; mt++)
                #pragma unroll
                for (int nt = 0; nt < 2; nt++)
                    acc[mt][nt] = __builtin_amdgcn_mfma_f32_16x16x32_bf16(wf[mt], sf[nt], acc[mt][nt], 0, 0, 0);
        }
    }
    #pragma unroll
    for (int mt = 0; mt < 4; mt++) {
        #pragma unroll
        for (int r = 0; r < 4; r++) {
            int o = o0 + wr * 64 + mt * 16 + lq * 4 + r;
            float bb = bias[o];
            #pragma unroll
            for (int nt = 0; nt < 2; nt++) {
                int s = s0 + wc * 32 + nt * 16 + lm;
                if (s < NN) {
                    int sb = s / OPLANE;
                    int soff = s - sb * OPLANE;
                    score[(sb * 256 + o) * OPLANE + soff] = acc[mt][nt][r] + bb;
                }
            }
        }
    }
}

extern "C" void kernel_launch(void* const* d_in, const int* in_sizes, int n_in,
                              void* d_out, int out_size, void* d_ws, size_t ws_size,
                              hipStream_t stream) {
    const float* x  = (const float*)d_in[0];
    const float* w0 = (const float*)d_in[1];
    const float* b0 = (const float*)d_in[2];
    const float* w1 = (const float*)d_in[3];
    const float* lw = (const float*)d_in[4];
    const float* lb = (const float*)d_in[5];
    const int* check = (const int*)d_in[6];

    float* out   = (float*)d_out;
    float* score = out;                    // 8*256*54*54 = 5,971,968
    float* o_th  = out + 5971968;          // 139,968
    float* o_out = out + 6111936;          // 139,968
    float* o_ax  = out + 6251904;          // 209,952
    float* o_ay  = out + 6461856;          // 209,952

    char* wsb = (char*)d_ws;
    unsigned short* h   = (unsigned short*)wsb;                  //   6,422,528 B (bf16)
    unsigned short* xnh = (unsigned short*)(wsb + 12845056);     //   6,422,528 B
    unsigned short* b1t = (unsigned short*)(wsb + 19267584);     //     294,912 B
    unsigned short* b2t = (unsigned short*)(wsb + 19562496);     //     589,824 B
    float* sxy = (float*)(wsb + 20152320);                       //   1,679,616 B -> 21.8 MB total

    k_pre<<<2176, 256, 0, stream>>>(x, w0, lw, xnh, b1t, b2t);
    k_gemm1<<<392, 512, 0, stream>>>(xnh, b1t, b0, h);
    k_conv2f<<<1464, 256, 0, stream>>>(h, w1, check, o_out, o_th, o_ax, o_ay, sxy);
    k_sgemm<<<736, 256, 0, stream>>>(xnh, b2t, lb, sxy, score);
}